// Round 1
// baseline (1270.395 us; speedup 1.0000x reference)
//
#include <hip/hip_runtime.h>
#include <hip/hip_bf16.h>

typedef __attribute__((ext_vector_type(8))) short bf16x8;   // 8 bf16 in 4 VGPRs
typedef __attribute__((ext_vector_type(4))) float f32x4;    // MFMA accumulator

#define NB 256
#define NT 200
#define NW 200
#define NE 768
#define NH 256
#define NEMB 32
#define KIN 800           // E + EMB
#define G3H 768           // 3*H
#define MROWS 51200       // B*T

__device__ __forceinline__ float bf2f(unsigned short h) {
    return __uint_as_float(((unsigned)h) << 16);
}
__device__ __forceinline__ unsigned short f2bf(float f) {
    unsigned u = __float_as_uint(f);
    u += 0x7fff + ((u >> 16) & 1);   // RNE
    return (unsigned short)(u >> 16);
}
__device__ __forceinline__ float sigm(float x) { return 1.0f / (1.0f + __expf(-x)); }
__device__ __forceinline__ float tanh_fast(float x) {
    float e = __expf(2.0f * x);
    return 1.0f - 2.0f / (e + 1.0f);
}

// ---------------------------------------------------------------------------
// prep1: A_bf16[51200][800] = [bf16(inputs) | bf16(emb_table[fix])],
//        W_ih -> bf16 [768][800], W_out -> bf16 [768][256]
// ---------------------------------------------------------------------------
__global__ void prep1(const float* __restrict__ inputs, const int* __restrict__ fix_seq,
                      const float* __restrict__ emb, const float* __restrict__ Wih,
                      const float* __restrict__ Wout,
                      unsigned short* __restrict__ Abf, unsigned short* __restrict__ Wihbf,
                      unsigned short* __restrict__ Woutbf) {
    const long NA = (long)MROWS * 100;   // 8 cols per unit
    const long NWU = 768L * 100;
    const long NOU = 768L * 32;
    const long total = NA + NWU + NOU;
    for (long u = (long)blockIdx.x * blockDim.x + threadIdx.x; u < total;
         u += (long)gridDim.x * blockDim.x) {
        bf16x8 v;
        unsigned short* dst;
        if (u < NA) {
            long row = u / 100;
            int c8 = (int)(u % 100) * 8;
            const float* s;
            if (c8 < NE) {
                s = inputs + row * NE + c8;
            } else {
                int fx = fix_seq[row];
                s = emb + (long)fx * NEMB + (c8 - NE);
            }
            #pragma unroll
            for (int j = 0; j < 8; j++) v[j] = (short)f2bf(s[j]);
            dst = Abf + row * KIN + c8;
        } else if (u < NA + NWU) {
            long u2 = u - NA;
            long row = u2 / 100;
            int c8 = (int)(u2 % 100) * 8;
            const float* s = Wih + row * KIN + c8;
            #pragma unroll
            for (int j = 0; j < 8; j++) v[j] = (short)f2bf(s[j]);
            dst = Wihbf + row * KIN + c8;
        } else {
            long u3 = u - NA - NWU;
            long row = u3 / 32;
            int c8 = (int)(u3 % 32) * 8;
            const float* s = Wout + row * NH + c8;
            #pragma unroll
            for (int j = 0; j < 8; j++) v[j] = (short)f2bf(s[j]);
            dst = Woutbf + row * NH + c8;
        }
        *(bf16x8*)dst = v;
    }
}

// ---------------------------------------------------------------------------
// gemm_bt128: Out[M][N] (bf16) = A[M][K](bf16) * Bw[N][K](bf16)^T + bias
// BM=BN=128, BK=32, 256 threads (4 waves, each 64x64). Reg-staged LDS tiles.
// M%128==0, N%128==0, K%32==0 required.
// ---------------------------------------------------------------------------
__global__ void gemm_bt128(const unsigned short* __restrict__ A,
                           const unsigned short* __restrict__ Bw,
                           const float* __restrict__ bias,
                           unsigned short* __restrict__ Out,
                           int M, int N, int K) {
    __shared__ unsigned short As[128 * 32];
    __shared__ unsigned short Bs[128 * 32];
    const int nblk = N >> 7;
    const int m0 = (blockIdx.x / nblk) << 7;
    const int n0 = (blockIdx.x % nblk) << 7;
    const int tid = threadIdx.x;
    const int lane = tid & 63;
    const int wave = tid >> 6;
    const int wm = (wave >> 1) << 6;
    const int wn = (wave & 1) << 6;
    const int nk = K >> 5;

    const int srow = tid >> 1;
    const int sbyte = (tid & 1) << 5;
    const char* ga = (const char*)(A + (long)(m0 + srow) * K) + sbyte;
    const char* gb = (const char*)(Bw + (long)(n0 + srow) * K) + sbyte;
    char* la = (char*)As + srow * 64 + sbyte;
    char* lb = (char*)Bs + srow * 64 + sbyte;

    f32x4 acc[4][4] = {};

    bf16x8 ra0 = *(const bf16x8*)(ga);
    bf16x8 ra1 = *(const bf16x8*)(ga + 16);
    bf16x8 rb0 = *(const bf16x8*)(gb);
    bf16x8 rb1 = *(const bf16x8*)(gb + 16);

    for (int kt = 0; kt < nk; kt++) {
        __syncthreads();
        *(bf16x8*)(la) = ra0;      *(bf16x8*)(la + 16) = ra1;
        *(bf16x8*)(lb) = rb0;      *(bf16x8*)(lb + 16) = rb1;
        __syncthreads();
        if (kt + 1 < nk) {  // prefetch next tile into regs; latency hides under MFMA
            const char* pa = ga + (kt + 1) * 64;
            const char* pb = gb + (kt + 1) * 64;
            ra0 = *(const bf16x8*)(pa);      ra1 = *(const bf16x8*)(pa + 16);
            rb0 = *(const bf16x8*)(pb);      rb1 = *(const bf16x8*)(pb + 16);
        }
        bf16x8 af[4], bfr[4];
        #pragma unroll
        for (int mi = 0; mi < 4; mi++)
            af[mi] = *(const bf16x8*)((const char*)As +
                        (wm + mi * 16 + (lane & 15)) * 64 + ((lane >> 4) << 4));
        #pragma unroll
        for (int ni = 0; ni < 4; ni++)
            bfr[ni] = *(const bf16x8*)((const char*)Bs +
                        (wn + ni * 16 + (lane & 15)) * 64 + ((lane >> 4) << 4));
        #pragma unroll
        for (int mi = 0; mi < 4; mi++)
            #pragma unroll
            for (int ni = 0; ni < 4; ni++)
                acc[mi][ni] = __builtin_amdgcn_mfma_f32_16x16x32_bf16(
                                  af[mi], bfr[ni], acc[mi][ni], 0, 0, 0);
    }
    // epilogue: D col = lane&15, row = (lane>>4)*4 + r  (m89-verified layout)
    #pragma unroll
    for (int ni = 0; ni < 4; ni++) {
        const int col = n0 + wn + ni * 16 + (lane & 15);
        const float bv = bias[col];
        #pragma unroll
        for (int mi = 0; mi < 4; mi++) {
            const int row = m0 + wm + mi * 16 + ((lane >> 4) << 2);
            #pragma unroll
            for (int r = 0; r < 4; r++)
                Out[(long)(row + r) * N + col] = f2bf(acc[mi][ni][r] + bv);
        }
    }
}

// ---------------------------------------------------------------------------
// gru_scan: persistent blocks. 16 blocks x 512 threads (8 waves).
// Block owns 16 batch rows; W_hh (bf16) resident in VGPRs (48 frags/thread).
// h state in LDS: fp32 master + XOR-swizzled bf16 copy for MFMA A-frags.
// ---------------------------------------------------------------------------
__global__ __launch_bounds__(512, 2)
void gru_scan(const unsigned short* __restrict__ xg,   // [51200][768] bf16 (includes b_ih)
              const float* __restrict__ Whh,            // [768][256] fp32
              const float* __restrict__ bhh,            // [768]
              const int* __restrict__ lengths,          // [256]
              unsigned short* __restrict__ hout) {      // [51200][256] bf16 (masked)
    __shared__ unsigned short hbf[16 * 256];  // swizzled bf16 h
    __shared__ float h32[16 * 256];           // fp32 h master
    __shared__ float hg[16 * 768];            // h @ Whh^T + bhh
    const int tid = threadIdx.x;
    const int lane = tid & 63;
    const int wave = tid >> 6;
    const int b0 = blockIdx.x << 4;

    // resident W_hh fragments: wave owns N-slice [wave*96, wave*96+96)
    const int ncol = wave * 96 + (lane & 15);
    const int krow = (lane >> 4) << 3;
    bf16x8 wf[6][8];
    float bh[6];
    #pragma unroll
    for (int nt = 0; nt < 6; nt++) {
        bh[nt] = bhh[ncol + nt * 16];
        #pragma unroll
        for (int kt = 0; kt < 8; kt++) {
            const float* s = Whh + (long)(ncol + nt * 16) * NH + kt * 32 + krow;
            bf16x8 v;
            #pragma unroll
            for (int j = 0; j < 8; j++) v[j] = (short)f2bf(s[j]);
            wf[nt][kt] = v;
        }
    }

    // gate-element mapping: unit = tid + it*512 -> (b = unit>>7, jpair = unit&127)
    const int j2 = (tid & 127) * 2;
    const int bbase = tid >> 7;   // 0..3
    int lens[4];
    #pragma unroll
    for (int it = 0; it < 4; it++) lens[it] = lengths[b0 + bbase + it * 4];

    for (int i = tid; i < 16 * 256; i += 512) h32[i] = 0.0f;
    for (int i = tid; i < 16 * 128; i += 512) ((unsigned*)hbf)[i] = 0u;
    __syncthreads();

    for (int t = 0; t < NT; t++) {
        // phase0: issue xg loads early (complete under MFMA phase)
        unsigned xv[4][3];
        #pragma unroll
        for (int it = 0; it < 4; it++) {
            const long row = (long)(b0 + bbase + it * 4) * NT + t;
            const unsigned short* xp = xg + row * G3H + j2;
            xv[it][0] = *(const unsigned*)(xp);
            xv[it][1] = *(const unsigned*)(xp + 256);
            xv[it][2] = *(const unsigned*)(xp + 512);
        }
        // phase1: hg = h_{t-1} @ Whh^T
        f32x4 acc[6] = {};
        #pragma unroll
        for (int kt = 0; kt < 8; kt++) {
            const int arow = lane & 15;
            const int abyte = arow * 512 + ((kt * 64 + ((lane >> 4) << 4)) ^ ((arow & 7) << 4));
            bf16x8 af = *(const bf16x8*)((const char*)hbf + abyte);
            #pragma unroll
            for (int nt = 0; nt < 6; nt++)
                acc[nt] = __builtin_amdgcn_mfma_f32_16x16x32_bf16(af, wf[nt][kt], acc[nt], 0, 0, 0);
        }
        // phase2: hg -> LDS (+ b_hh)
        #pragma unroll
        for (int nt = 0; nt < 6; nt++) {
            const int col = wave * 96 + nt * 16 + (lane & 15);
            #pragma unroll
            for (int r = 0; r < 4; r++)
                hg[(((lane >> 4) << 2) + r) * G3H + col] = acc[nt][r] + bh[nt];
        }
        __syncthreads();
        // phase3: gates + state update (each thread owns 4 (b, jpair) units)
        #pragma unroll
        for (int it = 0; it < 4; it++) {
            const int b = bbase + it * 4;
            const float* hgp = hg + b * G3H + j2;
            const float hr0 = hgp[0],   hr1 = hgp[1];
            const float hz0 = hgp[256], hz1 = hgp[257];
            const float hn0 = hgp[512], hn1 = hgp[513];
            const float xr0 = bf2f((unsigned short)(xv[it][0] & 0xffff));
            const float xr1 = bf2f((unsigned short)(xv[it][0] >> 16));
            const float xz0 = bf2f((unsigned short)(xv[it][1] & 0xffff));
            const float xz1 = bf2f((unsigned short)(xv[it][1] >> 16));
            const float xn0 = bf2f((unsigned short)(xv[it][2] & 0xffff));
            const float xn1 = bf2f((unsigned short)(xv[it][2] >> 16));
            const float hp0 = h32[b * NH + j2], hp1 = h32[b * NH + j2 + 1];
            const float r0 = sigm(xr0 + hr0), r1 = sigm(xr1 + hr1);
            const float z0 = sigm(xz0 + hz0), z1 = sigm(xz1 + hz1);
            const float n0 = tanh_fast(xn0 + r0 * hn0), n1 = tanh_fast(xn1 + r1 * hn1);
            const float hnew0 = (1.0f - z0) * n0 + z0 * hp0;
            const float hnew1 = (1.0f - z1) * n1 + z1 * hp1;
            h32[b * NH + j2] = hnew0;
            h32[b * NH + j2 + 1] = hnew1;
            const unsigned pack = (unsigned)f2bf(hnew0) | ((unsigned)f2bf(hnew1) << 16);
            *(unsigned*)((char*)hbf + b * 512 + ((j2 * 2) ^ ((b & 7) << 4))) = pack;
            const unsigned opack = (t < lens[it]) ? pack : 0u;  // pad_packed mask
            *(unsigned*)(hout + ((long)(b0 + b) * NT + t) * NH + j2) = opack;
        }
        __syncthreads();
    }
}

// ---------------------------------------------------------------------------
// prep2: fwe fp32 -> bf16 + word_mask (sum|row| != 0). One wave per row.
// ---------------------------------------------------------------------------
__global__ void prep2(const float* __restrict__ fwe, unsigned short* __restrict__ fwebf,
                      unsigned char* __restrict__ wmask) {
    const int row = (int)((blockIdx.x * blockDim.x + threadIdx.x) >> 6);
    const int lane = threadIdx.x & 63;
    if (row >= MROWS) return;
    const float* s = fwe + (long)row * NE;
    unsigned short* d = fwebf + (long)row * NE;
    float asum = 0.0f;
    #pragma unroll
    for (int i = 0; i < 12; i++) {
        const float v = s[lane + i * 64];
        asum += fabsf(v);
        d[lane + i * 64] = f2bf(v);
    }
    #pragma unroll
    for (int off = 32; off >= 1; off >>= 1) asum += __shfl_xor(asum, off);
    if (lane == 0) wmask[row] = (asum != 0.0f) ? 1 : 0;
}

// ---------------------------------------------------------------------------
// logits_gemm: per-batch GEMM [200 x 768] x [200 x 768]^T with mask epilogue.
// 64x64 tiles, 4 waves of 32x32. grid = 256 * 4 * 4.
// ---------------------------------------------------------------------------
__global__ void logits_gemm(const unsigned short* __restrict__ Aproj,  // [51200][768]
                            const unsigned short* __restrict__ Bfwe,   // [51200][768]
                            const int* __restrict__ fix_seq,           // [256][200]
                            const unsigned char* __restrict__ wmask,   // [51200]
                            float* __restrict__ out) {
    __shared__ unsigned short As[64 * 32];
    __shared__ unsigned short Bs[64 * 32];
    const int blk = blockIdx.x;
    const int b = blk >> 4;
    const int mt = (blk >> 2) & 3;
    const int ntile = blk & 3;
    const int t0 = mt << 6;
    const int w0 = ntile << 6;
    const int tid = threadIdx.x;
    const int lane = tid & 63;
    const int wave = tid >> 6;
    const int wm = (wave >> 1) << 5;
    const int wn = (wave & 1) << 5;

    const int srow = tid >> 2;
    const int sbyte = (tid & 3) << 4;
    const int tA = t0 + srow > 199 ? 199 : t0 + srow;   // clamp OOB rows (masked later)
    const int wB = w0 + srow > 199 ? 199 : w0 + srow;
    const char* ga = (const char*)(Aproj + ((long)b * NT + tA) * NE) + sbyte;
    const char* gb = (const char*)(Bfwe + ((long)b * NW + wB) * NE) + sbyte;
    char* la = (char*)As + srow * 64 + sbyte;
    char* lb = (char*)Bs + srow * 64 + sbyte;

    f32x4 acc[2][2] = {};
    bf16x8 ra = *(const bf16x8*)(ga);
    bf16x8 rb = *(const bf16x8*)(gb);
    for (int kt = 0; kt < 24; kt++) {
        __syncthreads();
        *(bf16x8*)(la) = ra;
        *(bf16x8*)(lb) = rb;
        __syncthreads();
        if (kt < 23) {
            ra = *(const bf16x8*)(ga + (kt + 1) * 64);
            rb = *(const bf16x8*)(gb + (kt + 1) * 64);
        }
        bf16x8 af[2], bfr[2];
        #pragma unroll
        for (int mi = 0; mi < 2; mi++)
            af[mi] = *(const bf16x8*)((const char*)As +
                        (wm + mi * 16 + (lane & 15)) * 64 + ((lane >> 4) << 4));
        #pragma unroll
        for (int ni = 0; ni < 2; ni++)
            bfr[ni] = *(const bf16x8*)((const char*)Bs +
                        (wn + ni * 16 + (lane & 15)) * 64 + ((lane >> 4) << 4));
        #pragma unroll
        for (int mi = 0; mi < 2; mi++)
            #pragma unroll
            for (int ni = 0; ni < 2; ni++)
                acc[mi][ni] = __builtin_amdgcn_mfma_f32_16x16x32_bf16(
                                  af[mi], bfr[ni], acc[mi][ni], 0, 0, 0);
    }
    // epilogue with saccade-window + valid + word masks
    #pragma unroll
    for (int mi = 0; mi < 2; mi++) {
        #pragma unroll
        for (int r = 0; r < 4; r++) {
            const int t = t0 + wm + mi * 16 + ((lane >> 4) << 2) + r;
            if (t >= NT) continue;
            const int fx = fix_seq[b * NT + t];
            #pragma unroll
            for (int ni = 0; ni < 2; ni++) {
                const int w = w0 + wn + ni * 16 + (lane & 15);
                if (w >= NW) continue;
                int d = w - fx; d = d < 0 ? -d : d;
                const bool ok = (fx != 0) && (d <= 8) && (wmask[b * NW + w] != 0);
                out[(long)b * (NT * NW) + t * NW + w] = ok ? acc[mi][ni][r] : -1e9f;
            }
        }
    }
}

// ---------------------------------------------------------------------------
// dur_kernel: dur[b,t] = dot(hout[b,t,:], W_dur) + b_dur. One wave per row.
// ---------------------------------------------------------------------------
__global__ void dur_kernel(const unsigned short* __restrict__ hout,
                           const float* __restrict__ Wdur, const float* __restrict__ bdur,
                           float* __restrict__ out) {
    const int row = (int)((blockIdx.x * blockDim.x + threadIdx.x) >> 6);
    const int lane = threadIdx.x & 63;
    if (row >= MROWS) return;
    const unsigned short* hp = hout + (long)row * NH + lane * 4;
    const uint2 hv = *(const uint2*)hp;
    const float4 wv = *(const float4*)(Wdur + lane * 4);
    float s = bf2f((unsigned short)(hv.x & 0xffff)) * wv.x
            + bf2f((unsigned short)(hv.x >> 16)) * wv.y
            + bf2f((unsigned short)(hv.y & 0xffff)) * wv.z
            + bf2f((unsigned short)(hv.y >> 16)) * wv.w;
    #pragma unroll
    for (int off = 32; off >= 1; off >>= 1) s += __shfl_down(s, off);
    if (lane == 0) out[(long)NB * NT * NW + row] = s + bdur[0];
}

// ---------------------------------------------------------------------------
extern "C" void kernel_launch(void* const* d_in, const int* in_sizes, int n_in,
                              void* d_out, int out_size, void* d_ws, size_t ws_size,
                              hipStream_t stream) {
    (void)in_sizes; (void)n_in; (void)out_size; (void)ws_size;
    const float* inputs  = (const float*)d_in[0];
    const int*   fix_seq = (const int*)d_in[1];
    const float* fwe     = (const float*)d_in[2];
    const int*   lengths = (const int*)d_in[3];
    const float* emb     = (const float*)d_in[5];
    const float* Wih     = (const float*)d_in[6];
    const float* bih     = (const float*)d_in[7];
    const float* Whh     = (const float*)d_in[8];
    const float* bhh     = (const float*)d_in[9];
    const float* Wout    = (const float*)d_in[10];
    const float* bout    = (const float*)d_in[11];
    const float* Wdur    = (const float*)d_in[12];
    const float* bdur    = (const float*)d_in[13];
    float* out = (float*)d_out;

    char* ws = (char*)d_ws;
    // region layout (bytes, all 256-aligned):
    //   [0, 81,920,000)           A_bf16 [51200][800]     -> reused as proj_bf16 [51200][768]
    //   [81,920,000, +78,643,200) xg_bf16 [51200][768]    -> reused as fwe_bf16
    //   [160,563,200, +26,214,400) hout_bf16 [51200][256]
    //   [186,777,600, +1,228,800)  W_ih bf16
    //   [188,006,400, +393,216)    W_out bf16
    //   [188,399,616, +51,200)     word_mask u8
    unsigned short* Abf    = (unsigned short*)(ws);
    unsigned short* xgbf   = (unsigned short*)(ws + 81920000);
    unsigned short* hout   = (unsigned short*)(ws + 160563200);
    unsigned short* Wihbf  = (unsigned short*)(ws + 186777600);
    unsigned short* Woutbf = (unsigned short*)(ws + 188006400);
    unsigned char*  wmask  = (unsigned char*)(ws + 188399616);
    unsigned short* projbf = Abf;    // A dead after gemmA
    unsigned short* fwebf  = xgbf;   // xg dead after scan

    prep1<<<2048, 256, 0, stream>>>(inputs, fix_seq, emb, Wih, Wout, Abf, Wihbf, Woutbf);
    gemm_bt128<<<400 * 6, 256, 0, stream>>>(Abf, Wihbf, bih, xgbf, MROWS, G3H, KIN);
    gru_scan<<<16, 512, 0, stream>>>(xgbf, Whh, bhh, lengths, hout);
    gemm_bt128<<<400 * 6, 256, 0, stream>>>(hout, Woutbf, bout, projbf, MROWS, G3H, NH);
    prep2<<<12800, 256, 0, stream>>>(fwe, fwebf, wmask);
    logits_gemm<<<4096, 256, 0, stream>>>(projbf, fwebf, fix_seq, wmask, out);
    dur_kernel<<<12800, 256, 0, stream>>>(hout, Wdur, bdur, out);
}

// Round 2
// 899.185 us; speedup vs baseline: 1.4128x; 1.4128x over previous
//
#include <hip/hip_runtime.h>
#include <hip/hip_bf16.h>

typedef __attribute__((ext_vector_type(8))) short bf16x8;   // 8 bf16 in 4 VGPRs
typedef __attribute__((ext_vector_type(4))) float f32x4;    // MFMA accumulator

#define NB 256
#define NT 200
#define NW 200
#define NE 768
#define NH 256
#define NEMB 32
#define KIN 800           // E + EMB
#define G3H 768           // 3*H
#define MROWS 51200       // B*T

__device__ __forceinline__ float bf2f(unsigned short h) {
    return __uint_as_float(((unsigned)h) << 16);
}
__device__ __forceinline__ unsigned short f2bf(float f) {
    unsigned u = __float_as_uint(f);
    u += 0x7fff + ((u >> 16) & 1);   // RNE
    return (unsigned short)(u >> 16);
}
__device__ __forceinline__ float sigm(float x) { return 1.0f / (1.0f + __expf(-x)); }
__device__ __forceinline__ float tanh_fast(float x) {
    float e = __expf(2.0f * x);
    return 1.0f - 2.0f / (e + 1.0f);
}

// ---------------------------------------------------------------------------
// prep1: A_bf16[51200][800] = [bf16(inputs) | bf16(emb_table[fix])],
//        W_ih -> bf16 [768][800], W_out -> bf16 [768][256]
// ---------------------------------------------------------------------------
__global__ void prep1(const float* __restrict__ inputs, const int* __restrict__ fix_seq,
                      const float* __restrict__ emb, const float* __restrict__ Wih,
                      const float* __restrict__ Wout,
                      unsigned short* __restrict__ Abf, unsigned short* __restrict__ Wihbf,
                      unsigned short* __restrict__ Woutbf) {
    const long NA = (long)MROWS * 100;   // 8 cols per unit
    const long NWU = 768L * 100;
    const long NOU = 768L * 32;
    const long total = NA + NWU + NOU;
    for (long u = (long)blockIdx.x * blockDim.x + threadIdx.x; u < total;
         u += (long)gridDim.x * blockDim.x) {
        bf16x8 v;
        unsigned short* dst;
        if (u < NA) {
            long row = u / 100;
            int c8 = (int)(u % 100) * 8;
            const float* s;
            if (c8 < NE) {
                s = inputs + row * NE + c8;
            } else {
                int fx = fix_seq[row];
                s = emb + (long)fx * NEMB + (c8 - NE);
            }
            #pragma unroll
            for (int j = 0; j < 8; j++) v[j] = (short)f2bf(s[j]);
            dst = Abf + row * KIN + c8;
        } else if (u < NA + NWU) {
            long u2 = u - NA;
            long row = u2 / 100;
            int c8 = (int)(u2 % 100) * 8;
            const float* s = Wih + row * KIN + c8;
            #pragma unroll
            for (int j = 0; j < 8; j++) v[j] = (short)f2bf(s[j]);
            dst = Wihbf + row * KIN + c8;
        } else {
            long u3 = u - NA - NWU;
            long row = u3 / 32;
            int c8 = (int)(u3 % 32) * 8;
            const float* s = Wout + row * NH + c8;
            #pragma unroll
            for (int j = 0; j < 8; j++) v[j] = (short)f2bf(s[j]);
            dst = Woutbf + row * NH + c8;
        }
        *(bf16x8*)dst = v;
    }
}

// ---------------------------------------------------------------------------
// gemm_bt128: Out[M][N] (bf16) = A[M][K](bf16) * Bw[N][K](bf16)^T + bias
// BM=BN=128, BK=32, 256 threads (4 waves, each 64x64). Reg-staged LDS tiles.
// ---------------------------------------------------------------------------
__global__ void gemm_bt128(const unsigned short* __restrict__ A,
                           const unsigned short* __restrict__ Bw,
                           const float* __restrict__ bias,
                           unsigned short* __restrict__ Out,
                           int M, int N, int K) {
    __shared__ unsigned short As[128 * 32];
    __shared__ unsigned short Bs[128 * 32];
    const int nblk = N >> 7;
    const int m0 = (blockIdx.x / nblk) << 7;
    const int n0 = (blockIdx.x % nblk) << 7;
    const int tid = threadIdx.x;
    const int lane = tid & 63;
    const int wave = tid >> 6;
    const int wm = (wave >> 1) << 6;
    const int wn = (wave & 1) << 6;
    const int nk = K >> 5;

    const int srow = tid >> 1;
    const int sbyte = (tid & 1) << 5;
    const char* ga = (const char*)(A + (long)(m0 + srow) * K) + sbyte;
    const char* gb = (const char*)(Bw + (long)(n0 + srow) * K) + sbyte;
    char* la = (char*)As + srow * 64 + sbyte;
    char* lb = (char*)Bs + srow * 64 + sbyte;

    f32x4 acc[4][4] = {};

    bf16x8 ra0 = *(const bf16x8*)(ga);
    bf16x8 ra1 = *(const bf16x8*)(ga + 16);
    bf16x8 rb0 = *(const bf16x8*)(gb);
    bf16x8 rb1 = *(const bf16x8*)(gb + 16);

    for (int kt = 0; kt < nk; kt++) {
        __syncthreads();
        *(bf16x8*)(la) = ra0;      *(bf16x8*)(la + 16) = ra1;
        *(bf16x8*)(lb) = rb0;      *(bf16x8*)(lb + 16) = rb1;
        __syncthreads();
        if (kt + 1 < nk) {  // prefetch next tile into regs; latency hides under MFMA
            const char* pa = ga + (kt + 1) * 64;
            const char* pb = gb + (kt + 1) * 64;
            ra0 = *(const bf16x8*)(pa);      ra1 = *(const bf16x8*)(pa + 16);
            rb0 = *(const bf16x8*)(pb);      rb1 = *(const bf16x8*)(pb + 16);
        }
        bf16x8 af[4], bfr[4];
        #pragma unroll
        for (int mi = 0; mi < 4; mi++)
            af[mi] = *(const bf16x8*)((const char*)As +
                        (wm + mi * 16 + (lane & 15)) * 64 + ((lane >> 4) << 4));
        #pragma unroll
        for (int ni = 0; ni < 4; ni++)
            bfr[ni] = *(const bf16x8*)((const char*)Bs +
                        (wn + ni * 16 + (lane & 15)) * 64 + ((lane >> 4) << 4));
        #pragma unroll
        for (int mi = 0; mi < 4; mi++)
            #pragma unroll
            for (int ni = 0; ni < 4; ni++)
                acc[mi][ni] = __builtin_amdgcn_mfma_f32_16x16x32_bf16(
                                  af[mi], bfr[ni], acc[mi][ni], 0, 0, 0);
    }
    // epilogue: D col = lane&15, row = (lane>>4)*4 + r  (m89-verified layout)
    #pragma unroll
    for (int ni = 0; ni < 4; ni++) {
        const int col = n0 + wn + ni * 16 + (lane & 15);
        const float bv = bias[col];
        #pragma unroll
        for (int mi = 0; mi < 4; mi++) {
            const int row = m0 + wm + mi * 16 + ((lane >> 4) << 2);
            #pragma unroll
            for (int r = 0; r < 4; r++)
                Out[(long)(row + r) * N + col] = f2bf(acc[mi][ni][r] + bv);
        }
    }
}

// ---------------------------------------------------------------------------
// gru_scan: 256 blocks (1 batch each), 512 threads (8 waves), 1 block/CU.
// Wave w owns h-cols [32w, 32w+32): its 6 W_hh B-frags are the r/z/n rows of
// those columns, so after the MFMA lanes 0-15 hold all 3 gates for their own
// 2 h-cols -> gate math is lane-local. No hg exchange, 1 barrier/step.
// h_prev fp32 in registers; bf16 h double-buffered in LDS (XOR-swizzled rows).
// ---------------------------------------------------------------------------
__global__ __launch_bounds__(512, 2)
void gru_scan(const unsigned short* __restrict__ xg,   // [51200][768] bf16 (incl b_ih)
              const float* __restrict__ Whh,            // [768][256] fp32
              const float* __restrict__ bhh,            // [768]
              const int* __restrict__ lengths,          // [256]
              unsigned short* __restrict__ hout) {      // [51200][256] bf16 (masked)
    __shared__ unsigned short hbf[2][16 * 256];  // row 0 live, rows 1-15 stay zero
    const int tid = threadIdx.x;
    const int lane = tid & 63;
    const int wave = tid >> 6;
    const int b = blockIdx.x;
    const int l = lane & 15;
    const int c0 = wave * 32 + l;          // this lane's first h-col (lanes 0-15)

    // W_hh resident fragments: nt -> global N-row (nt>>1)*256 + wave*32 + (nt&1)*16 + l
    bf16x8 wf[6][8];
    float bh[6];
    #pragma unroll
    for (int nt = 0; nt < 6; nt++) {
        const int nrow = (nt >> 1) * 256 + wave * 32 + ((nt & 1) << 4) + l;
        bh[nt] = bhh[nrow];
        #pragma unroll
        for (int kt = 0; kt < 8; kt++) {
            const float* s = Whh + (long)nrow * NH + kt * 32 + ((lane >> 4) << 3);
            bf16x8 v;
            #pragma unroll
            for (int j = 0; j < 8; j++) v[j] = (short)f2bf(s[j]);
            wf[nt][kt] = v;
        }
    }

    const int len = lengths[b];
    for (int i = tid; i < 2 * 16 * 128; i += 512) ((unsigned*)hbf)[i] = 0u;
    __syncthreads();

    float hp0 = 0.0f, hp1 = 0.0f;
    const unsigned short* xrow = xg + (long)b * NT * G3H;
    const bool gl = (lane < 16);
    unsigned short xv[6];
    if (gl) {
        #pragma unroll
        for (int g = 0; g < 6; g++) xv[g] = xrow[(g >> 1) * 256 + ((g & 1) << 4) + c0];
    }

    for (int t = 0; t < NT; t++) {
        // MFMA: hg slice for this wave's h-cols. Read h_{t-1} from hbf[(t+1)&1].
        f32x4 acc[6] = {};
        const char* hb = (const char*)hbf[(t + 1) & 1];
        #pragma unroll
        for (int kt = 0; kt < 8; kt++) {
            const int arow = lane & 15;
            const int abyte = arow * 512 + ((kt * 64 + ((lane >> 4) << 4)) ^ ((arow & 7) << 4));
            bf16x8 af = *(const bf16x8*)(hb + abyte);
            #pragma unroll
            for (int nt = 0; nt < 6; nt++)
                acc[nt] = __builtin_amdgcn_mfma_f32_16x16x32_bf16(af, wf[nt][kt], acc[nt], 0, 0, 0);
        }
        // lane-local gates for batch row 0 (acc[.][0])
        if (gl) {
            const float r0 = sigm(bf2f(xv[0]) + acc[0][0] + bh[0]);
            const float r1 = sigm(bf2f(xv[1]) + acc[1][0] + bh[1]);
            const float z0 = sigm(bf2f(xv[2]) + acc[2][0] + bh[2]);
            const float z1 = sigm(bf2f(xv[3]) + acc[3][0] + bh[3]);
            const float n0 = tanh_fast(bf2f(xv[4]) + r0 * (acc[4][0] + bh[4]));
            const float n1 = tanh_fast(bf2f(xv[5]) + r1 * (acc[5][0] + bh[5]));
            hp0 = (1.0f - z0) * n0 + z0 * hp0;
            hp1 = (1.0f - z1) * n1 + z1 * hp1;
            const unsigned short h0 = f2bf(hp0), h1 = f2bf(hp1);
            unsigned short* wb = hbf[t & 1];       // row 0: swizzle is identity
            wb[c0] = h0;
            wb[c0 + 16] = h1;
            unsigned short* op = hout + ((long)b * NT + t) * NH;
            const bool keep = (t < len);
            op[c0] = keep ? h0 : (unsigned short)0;
            op[c0 + 16] = keep ? h1 : (unsigned short)0;
            if (t + 1 < NT) {                      // prefetch next step's xg
                const unsigned short* xn = xrow + (long)(t + 1) * G3H;
                #pragma unroll
                for (int g = 0; g < 6; g++) xv[g] = xn[(g >> 1) * 256 + ((g & 1) << 4) + c0];
            }
        }
        __syncthreads();
    }
}

// ---------------------------------------------------------------------------
// prep2: fwe fp32 -> bf16 + word_mask (sum|row| != 0). One wave per row.
// ---------------------------------------------------------------------------
__global__ void prep2(const float* __restrict__ fwe, unsigned short* __restrict__ fwebf,
                      unsigned char* __restrict__ wmask) {
    const int row = (int)((blockIdx.x * blockDim.x + threadIdx.x) >> 6);
    const int lane = threadIdx.x & 63;
    if (row >= MROWS) return;
    const float* s = fwe + (long)row * NE;
    unsigned short* d = fwebf + (long)row * NE;
    float asum = 0.0f;
    #pragma unroll
    for (int i = 0; i < 12; i++) {
        const float v = s[lane + i * 64];
        asum += fabsf(v);
        d[lane + i * 64] = f2bf(v);
    }
    #pragma unroll
    for (int off = 32; off >= 1; off >>= 1) asum += __shfl_xor(asum, off);
    if (lane == 0) wmask[row] = (asum != 0.0f) ? 1 : 0;
}

// ---------------------------------------------------------------------------
// logits_gemm: per-batch GEMM [200 x 768] x [200 x 768]^T with mask epilogue.
// ---------------------------------------------------------------------------
__global__ void logits_gemm(const unsigned short* __restrict__ Aproj,  // [51200][768]
                            const unsigned short* __restrict__ Bfwe,   // [51200][768]
                            const int* __restrict__ fix_seq,           // [256][200]
                            const unsigned char* __restrict__ wmask,   // [51200]
                            float* __restrict__ out) {
    __shared__ unsigned short As[64 * 32];
    __shared__ unsigned short Bs[64 * 32];
    const int blk = blockIdx.x;
    const int b = blk >> 4;
    const int mt = (blk >> 2) & 3;
    const int ntile = blk & 3;
    const int t0 = mt << 6;
    const int w0 = ntile << 6;
    const int tid = threadIdx.x;
    const int lane = tid & 63;
    const int wave = tid >> 6;
    const int wm = (wave >> 1) << 5;
    const int wn = (wave & 1) << 5;

    const int srow = tid >> 2;
    const int sbyte = (tid & 3) << 4;
    const int tA = t0 + srow > 199 ? 199 : t0 + srow;   // clamp OOB rows (masked later)
    const int wB = w0 + srow > 199 ? 199 : w0 + srow;
    const char* ga = (const char*)(Aproj + ((long)b * NT + tA) * NE) + sbyte;
    const char* gb = (const char*)(Bfwe + ((long)b * NW + wB) * NE) + sbyte;
    char* la = (char*)As + srow * 64 + sbyte;
    char* lb = (char*)Bs + srow * 64 + sbyte;

    f32x4 acc[2][2] = {};
    bf16x8 ra = *(const bf16x8*)(ga);
    bf16x8 rb = *(const bf16x8*)(gb);
    for (int kt = 0; kt < 24; kt++) {
        __syncthreads();
        *(bf16x8*)(la) = ra;
        *(bf16x8*)(lb) = rb;
        __syncthreads();
        if (kt < 23) {
            ra = *(const bf16x8*)(ga + (kt + 1) * 64);
            rb = *(const bf16x8*)(gb + (kt + 1) * 64);
        }
        bf16x8 af[2], bfr[2];
        #pragma unroll
        for (int mi = 0; mi < 2; mi++)
            af[mi] = *(const bf16x8*)((const char*)As +
                        (wm + mi * 16 + (lane & 15)) * 64 + ((lane >> 4) << 4));
        #pragma unroll
        for (int ni = 0; ni < 2; ni++)
            bfr[ni] = *(const bf16x8*)((const char*)Bs +
                        (wn + ni * 16 + (lane & 15)) * 64 + ((lane >> 4) << 4));
        #pragma unroll
        for (int mi = 0; mi < 2; mi++)
            #pragma unroll
            for (int ni = 0; ni < 2; ni++)
                acc[mi][ni] = __builtin_amdgcn_mfma_f32_16x16x32_bf16(
                                  af[mi], bfr[ni], acc[mi][ni], 0, 0, 0);
    }
    // epilogue with saccade-window + valid + word masks
    #pragma unroll
    for (int mi = 0; mi < 2; mi++) {
        #pragma unroll
        for (int r = 0; r < 4; r++) {
            const int t = t0 + wm + mi * 16 + ((lane >> 4) << 2) + r;
            if (t >= NT) continue;
            const int fx = fix_seq[b * NT + t];
            #pragma unroll
            for (int ni = 0; ni < 2; ni++) {
                const int w = w0 + wn + ni * 16 + (lane & 15);
                if (w >= NW) continue;
                int d = w - fx; d = d < 0 ? -d : d;
                const bool ok = (fx != 0) && (d <= 8) && (wmask[b * NW + w] != 0);
                out[(long)b * (NT * NW) + t * NW + w] = ok ? acc[mi][ni][r] : -1e9f;
            }
        }
    }
}

// ---------------------------------------------------------------------------
// dur_kernel: dur[b,t] = dot(hout[b,t,:], W_dur) + b_dur. One wave per row.
// ---------------------------------------------------------------------------
__global__ void dur_kernel(const unsigned short* __restrict__ hout,
                           const float* __restrict__ Wdur, const float* __restrict__ bdur,
                           float* __restrict__ out) {
    const int row = (int)((blockIdx.x * blockDim.x + threadIdx.x) >> 6);
    const int lane = threadIdx.x & 63;
    if (row >= MROWS) return;
    const unsigned short* hp = hout + (long)row * NH + lane * 4;
    const uint2 hv = *(const uint2*)hp;
    const float4 wv = *(const float4*)(Wdur + lane * 4);
    float s = bf2f((unsigned short)(hv.x & 0xffff)) * wv.x
            + bf2f((unsigned short)(hv.x >> 16)) * wv.y
            + bf2f((unsigned short)(hv.y & 0xffff)) * wv.z
            + bf2f((unsigned short)(hv.y >> 16)) * wv.w;
    #pragma unroll
    for (int off = 32; off >= 1; off >>= 1) s += __shfl_down(s, off);
    if (lane == 0) out[(long)NB * NT * NW + row] = s + bdur[0];
}

// ---------------------------------------------------------------------------
extern "C" void kernel_launch(void* const* d_in, const int* in_sizes, int n_in,
                              void* d_out, int out_size, void* d_ws, size_t ws_size,
                              hipStream_t stream) {
    (void)in_sizes; (void)n_in; (void)out_size; (void)ws_size;
    const float* inputs  = (const float*)d_in[0];
    const int*   fix_seq = (const int*)d_in[1];
    const float* fwe     = (const float*)d_in[2];
    const int*   lengths = (const int*)d_in[3];
    const float* emb     = (const float*)d_in[5];
    const float* Wih     = (const float*)d_in[6];
    const float* bih     = (const float*)d_in[7];
    const float* Whh     = (const float*)d_in[8];
    const float* bhh     = (const float*)d_in[9];
    const float* Wout    = (const float*)d_in[10];
    const float* bout    = (const float*)d_in[11];
    const float* Wdur    = (const float*)d_in[12];
    const float* bdur    = (const float*)d_in[13];
    float* out = (float*)d_out;

    char* ws = (char*)d_ws;
    // region layout (bytes, all 256-aligned):
    //   [0, 81,920,000)            A_bf16 [51200][800]    -> reused as proj_bf16
    //   [81,920,000, +78,643,200)  xg_bf16 [51200][768]   -> reused as fwe_bf16
    //   [160,563,200, +26,214,400) hout_bf16 [51200][256]
    //   [186,777,600, +1,228,800)  W_ih bf16
    //   [188,006,400, +393,216)    W_out bf16
    //   [188,399,616, +51,200)     word_mask u8
    unsigned short* Abf    = (unsigned short*)(ws);
    unsigned short* xgbf   = (unsigned short*)(ws + 81920000);
    unsigned short* hout   = (unsigned short*)(ws + 160563200);
    unsigned short* Wihbf  = (unsigned short*)(ws + 186777600);
    unsigned short* Woutbf = (unsigned short*)(ws + 188006400);
    unsigned char*  wmask  = (unsigned char*)(ws + 188399616);
    unsigned short* projbf = Abf;    // A dead after gemm1
    unsigned short* fwebf  = xgbf;   // xg dead after scan

    prep1<<<2048, 256, 0, stream>>>(inputs, fix_seq, emb, Wih, Wout, Abf, Wihbf, Woutbf);
    gemm_bt128<<<400 * 6, 256, 0, stream>>>(Abf, Wihbf, bih, xgbf, MROWS, G3H, KIN);
    gru_scan<<<256, 512, 0, stream>>>(xgbf, Whh, bhh, lengths, hout);
    gemm_bt128<<<400 * 6, 256, 0, stream>>>(hout, Woutbf, bout, projbf, MROWS, G3H, NH);
    prep2<<<12800, 256, 0, stream>>>(fwe, fwebf, wmask);
    logits_gemm<<<4096, 256, 0, stream>>>(projbf, fwebf, fix_seq, wmask, out);
    dur_kernel<<<12800, 256, 0, stream>>>(hout, Wdur, bdur, out);
}

// Round 3
// 890.415 us; speedup vs baseline: 1.4267x; 1.0098x over previous
//
#include <hip/hip_runtime.h>
#include <hip/hip_bf16.h>

typedef __attribute__((ext_vector_type(8))) short bf16x8;   // 8 bf16 in 4 VGPRs
typedef __attribute__((ext_vector_type(4))) float f32x4;    // MFMA accumulator

#define NB 256
#define NT 200
#define NW 200
#define NE 768
#define NH 256
#define NEMB 32
#define KIN 800           // E + EMB
#define G3H 768           // 3*H
#define MROWS 51200       // B*T

__device__ __forceinline__ float bf2f(unsigned short h) {
    return __uint_as_float(((unsigned)h) << 16);
}
__device__ __forceinline__ unsigned short f2bf(float f) {
    unsigned u = __float_as_uint(f);
    u += 0x7fff + ((u >> 16) & 1);   // RNE
    return (unsigned short)(u >> 16);
}
__device__ __forceinline__ float sigm(float x) { return 1.0f / (1.0f + __expf(-x)); }
__device__ __forceinline__ float tanh_fast(float x) {
    float e = __expf(2.0f * x);
    return 1.0f - 2.0f / (e + 1.0f);
}

// ---------------------------------------------------------------------------
// prep1: A_bf16[51200][800] = [bf16(inputs) | bf16(emb_table[fix])],
//        W_ih -> bf16 [768][800], W_out -> bf16 [768][256]
// ---------------------------------------------------------------------------
__global__ void prep1(const float* __restrict__ inputs, const int* __restrict__ fix_seq,
                      const float* __restrict__ emb, const float* __restrict__ Wih,
                      const float* __restrict__ Wout,
                      unsigned short* __restrict__ Abf, unsigned short* __restrict__ Wihbf,
                      unsigned short* __restrict__ Woutbf) {
    const long NA = (long)MROWS * 100;   // 8 cols per unit
    const long NWU = 768L * 100;
    const long NOU = 768L * 32;
    const long total = NA + NWU + NOU;
    for (long u = (long)blockIdx.x * blockDim.x + threadIdx.x; u < total;
         u += (long)gridDim.x * blockDim.x) {
        bf16x8 v;
        unsigned short* dst;
        if (u < NA) {
            long row = u / 100;
            int c8 = (int)(u % 100) * 8;
            const float* s;
            if (c8 < NE) {
                s = inputs + row * NE + c8;
            } else {
                int fx = fix_seq[row];
                s = emb + (long)fx * NEMB + (c8 - NE);
            }
            #pragma unroll
            for (int j = 0; j < 8; j++) v[j] = (short)f2bf(s[j]);
            dst = Abf + row * KIN + c8;
        } else if (u < NA + NWU) {
            long u2 = u - NA;
            long row = u2 / 100;
            int c8 = (int)(u2 % 100) * 8;
            const float* s = Wih + row * KIN + c8;
            #pragma unroll
            for (int j = 0; j < 8; j++) v[j] = (short)f2bf(s[j]);
            dst = Wihbf + row * KIN + c8;
        } else {
            long u3 = u - NA - NWU;
            long row = u3 / 32;
            int c8 = (int)(u3 % 32) * 8;
            const float* s = Wout + row * NH + c8;
            #pragma unroll
            for (int j = 0; j < 8; j++) v[j] = (short)f2bf(s[j]);
            dst = Woutbf + row * NH + c8;
        }
        *(bf16x8*)dst = v;
    }
}

// ---------------------------------------------------------------------------
// gemm_bt128: Out[M][N] (bf16) = A[M][K](bf16) * Bw[N][K](bf16)^T + bias
// BM=BN=128, BK=32, 256 threads (4 waves, each 64x64). Reg-staged LDS tiles.
// ---------------------------------------------------------------------------
__global__ void gemm_bt128(const unsigned short* __restrict__ A,
                           const unsigned short* __restrict__ Bw,
                           const float* __restrict__ bias,
                           unsigned short* __restrict__ Out,
                           int M, int N, int K) {
    __shared__ unsigned short As[128 * 32];
    __shared__ unsigned short Bs[128 * 32];
    const int nblk = N >> 7;
    const int m0 = (blockIdx.x / nblk) << 7;
    const int n0 = (blockIdx.x % nblk) << 7;
    const int tid = threadIdx.x;
    const int lane = tid & 63;
    const int wave = tid >> 6;
    const int wm = (wave >> 1) << 6;
    const int wn = (wave & 1) << 6;
    const int nk = K >> 5;

    const int srow = tid >> 1;
    const int sbyte = (tid & 1) << 5;
    const char* ga = (const char*)(A + (long)(m0 + srow) * K) + sbyte;
    const char* gb = (const char*)(Bw + (long)(n0 + srow) * K) + sbyte;
    char* la = (char*)As + srow * 64 + sbyte;
    char* lb = (char*)Bs + srow * 64 + sbyte;

    f32x4 acc[4][4] = {};

    bf16x8 ra0 = *(const bf16x8*)(ga);
    bf16x8 ra1 = *(const bf16x8*)(ga + 16);
    bf16x8 rb0 = *(const bf16x8*)(gb);
    bf16x8 rb1 = *(const bf16x8*)(gb + 16);

    for (int kt = 0; kt < nk; kt++) {
        __syncthreads();
        *(bf16x8*)(la) = ra0;      *(bf16x8*)(la + 16) = ra1;
        *(bf16x8*)(lb) = rb0;      *(bf16x8*)(lb + 16) = rb1;
        __syncthreads();
        if (kt + 1 < nk) {  // prefetch next tile into regs; latency hides under MFMA
            const char* pa = ga + (kt + 1) * 64;
            const char* pb = gb + (kt + 1) * 64;
            ra0 = *(const bf16x8*)(pa);      ra1 = *(const bf16x8*)(pa + 16);
            rb0 = *(const bf16x8*)(pb);      rb1 = *(const bf16x8*)(pb + 16);
        }
        bf16x8 af[4], bfr[4];
        #pragma unroll
        for (int mi = 0; mi < 4; mi++)
            af[mi] = *(const bf16x8*)((const char*)As +
                        (wm + mi * 16 + (lane & 15)) * 64 + ((lane >> 4) << 4));
        #pragma unroll
        for (int ni = 0; ni < 4; ni++)
            bfr[ni] = *(const bf16x8*)((const char*)Bs +
                        (wn + ni * 16 + (lane & 15)) * 64 + ((lane >> 4) << 4));
        #pragma unroll
        for (int mi = 0; mi < 4; mi++)
            #pragma unroll
            for (int ni = 0; ni < 4; ni++)
                acc[mi][ni] = __builtin_amdgcn_mfma_f32_16x16x32_bf16(
                                  af[mi], bfr[ni], acc[mi][ni], 0, 0, 0);
    }
    // epilogue: D col = lane&15, row = (lane>>4)*4 + r  (m89-verified layout)
    #pragma unroll
    for (int ni = 0; ni < 4; ni++) {
        const int col = n0 + wn + ni * 16 + (lane & 15);
        const float bv = bias[col];
        #pragma unroll
        for (int mi = 0; mi < 4; mi++) {
            const int row = m0 + wm + mi * 16 + ((lane >> 4) << 2);
            #pragma unroll
            for (int r = 0; r < 4; r++)
                Out[(long)(row + r) * N + col] = f2bf(acc[mi][ni][r] + bv);
        }
    }
}

// ---------------------------------------------------------------------------
// gru_scan: 256 blocks (1 batch each), 512 threads (8 waves), 1 block/CU.
// Wave w owns h-cols [32w,32w+32): lanes 0-15 get all 3 gates for their own
// 2 cols -> lane-local gate math. h (bf16, 512B) double-buffered in LDS.
// Only lanes with (lane&15)==0 carry nonzero A-frags -> predicated ds_read.
// Barrier = lgkmcnt(0)+s_barrier ONLY (no vmcnt drain): hout stores and the
// 2-step-deep xg prefetch stay in flight across steps.
// ---------------------------------------------------------------------------
__global__ __launch_bounds__(512)
__attribute__((amdgpu_waves_per_eu(2, 2)))
void gru_scan(const unsigned short* __restrict__ xg,   // [51200][768] bf16 (incl b_ih)
              const float* __restrict__ Whh,            // [768][256] fp32
              const float* __restrict__ bhh,            // [768]
              const int* __restrict__ lengths,          // [256]
              unsigned short* __restrict__ hout) {      // [51200][256] bf16 (masked)
    __shared__ unsigned short hbf[2][256];   // h double buffer, 512 B each
    const int tid = threadIdx.x;
    const int lane = tid & 63;
    const int wave = tid >> 6;
    const int b = blockIdx.x;
    const int l = lane & 15;
    const int sub = lane >> 4;               // k-slice 0..3
    const int c0 = wave * 32 + l;            // this lane's first h-col

    // W_hh resident B-frags: nt -> rows (nt>>1)*256 + wave*32 + (nt&1)*16 + l
    bf16x8 wf[6][8];
    float bh[6];
    #pragma unroll
    for (int nt = 0; nt < 6; nt++) {
        const int nrow = (nt >> 1) * 256 + wave * 32 + ((nt & 1) << 4) + l;
        bh[nt] = bhh[nrow];
        #pragma unroll
        for (int kt = 0; kt < 8; kt++) {
            const float4 f0 = *(const float4*)(Whh + (long)nrow * NH + kt * 32 + sub * 8);
            const float4 f1 = *(const float4*)(Whh + (long)nrow * NH + kt * 32 + sub * 8 + 4);
            bf16x8 v;
            v[0] = (short)f2bf(f0.x); v[1] = (short)f2bf(f0.y);
            v[2] = (short)f2bf(f0.z); v[3] = (short)f2bf(f0.w);
            v[4] = (short)f2bf(f1.x); v[5] = (short)f2bf(f1.y);
            v[6] = (short)f2bf(f1.z); v[7] = (short)f2bf(f1.w);
            wf[nt][kt] = v;
        }
    }

    const int len = lengths[b];
    if (tid < 256) ((unsigned*)hbf)[tid] = 0u;   // zero both buffers (1024 B)

    const bool gl = (lane < 16);
    const unsigned short* xrow = xg + (long)b * NT * G3H;
    unsigned short xva[6], xvb[6];
    if (gl) {
        #pragma unroll
        for (int g = 0; g < 6; g++) {
            const int off = (g >> 1) * 256 + ((g & 1) << 4) + c0;
            xva[g] = xrow[off];              // t=0
            xvb[g] = xrow[G3H + off];        // t=1
        }
    }
    float hp0 = 0.0f, hp1 = 0.0f;

    asm volatile("s_waitcnt lgkmcnt(0)" ::: "memory");
    __builtin_amdgcn_sched_barrier(0);
    __builtin_amdgcn_s_barrier();
    __builtin_amdgcn_sched_barrier(0);

    auto step = [&](int t, unsigned short (&xv)[6]) {
        // MFMA: hg = h_{t-1} @ Whh^T (this wave's 32 cols x 3 gates)
        const char* hb = (const char*)(hbf[(t + 1) & 1]);
        f32x4 acc[6] = {};
        #pragma unroll
        for (int kt = 0; kt < 8; kt++) {
            bf16x8 af = {};
            if (l == 0)   // only A-row 0 is live (lanes 0,16,32,48)
                af = *(const bf16x8*)(hb + kt * 64 + (sub << 4));
            #pragma unroll
            for (int nt = 0; nt < 6; nt++)
                acc[nt] = __builtin_amdgcn_mfma_f32_16x16x32_bf16(af, wf[nt][kt], acc[nt], 0, 0, 0);
        }
        if (gl) {
            const float r0 = sigm(bf2f(xv[0]) + acc[0][0] + bh[0]);
            const float r1 = sigm(bf2f(xv[1]) + acc[1][0] + bh[1]);
            const float z0 = sigm(bf2f(xv[2]) + acc[2][0] + bh[2]);
            const float z1 = sigm(bf2f(xv[3]) + acc[3][0] + bh[3]);
            const float n0 = tanh_fast(bf2f(xv[4]) + r0 * (acc[4][0] + bh[4]));
            const float n1 = tanh_fast(bf2f(xv[5]) + r1 * (acc[5][0] + bh[5]));
            hp0 = (1.0f - z0) * n0 + z0 * hp0;
            hp1 = (1.0f - z1) * n1 + z1 * hp1;
            const unsigned short h0 = f2bf(hp0), h1 = f2bf(hp1);
            unsigned short* wb = hbf[t & 1];
            wb[c0] = h0;
            wb[c0 + 16] = h1;
            unsigned short* op = hout + ((long)b * NT + t) * NH;
            const bool keep = (t < len);
            op[c0] = keep ? h0 : (unsigned short)0;
            op[c0 + 16] = keep ? h1 : (unsigned short)0;
            if (t + 2 < NT) {                 // 2-deep prefetch: used 2 steps later
                const unsigned short* xn = xrow + (long)(t + 2) * G3H;
                #pragma unroll
                for (int g = 0; g < 6; g++)
                    xv[g] = xn[(g >> 1) * 256 + ((g & 1) << 4) + c0];
            }
        }
        // LDS-only baton: do NOT drain vmcnt (stores/prefetch float across steps)
        asm volatile("s_waitcnt lgkmcnt(0)" ::: "memory");
        __builtin_amdgcn_sched_barrier(0);
        __builtin_amdgcn_s_barrier();
        __builtin_amdgcn_sched_barrier(0);
    };

    for (int t = 0; t < NT; t += 2) {
        step(t, xva);
        step(t + 1, xvb);
    }
}

// ---------------------------------------------------------------------------
// prep2: fwe fp32 -> bf16 + word_mask (sum|row| != 0). One wave per row.
// ---------------------------------------------------------------------------
__global__ void prep2(const float* __restrict__ fwe, unsigned short* __restrict__ fwebf,
                      unsigned char* __restrict__ wmask) {
    const int row = (int)((blockIdx.x * blockDim.x + threadIdx.x) >> 6);
    const int lane = threadIdx.x & 63;
    if (row >= MROWS) return;
    const float* s = fwe + (long)row * NE;
    unsigned short* d = fwebf + (long)row * NE;
    float asum = 0.0f;
    #pragma unroll
    for (int i = 0; i < 12; i++) {
        const float v = s[lane + i * 64];
        asum += fabsf(v);
        d[lane + i * 64] = f2bf(v);
    }
    #pragma unroll
    for (int off = 32; off >= 1; off >>= 1) asum += __shfl_xor(asum, off);
    if (lane == 0) wmask[row] = (asum != 0.0f) ? 1 : 0;
}

// ---------------------------------------------------------------------------
// logits_gemm: per-batch GEMM [200 x 768] x [200 x 768]^T with mask epilogue.
// ---------------------------------------------------------------------------
__global__ void logits_gemm(const unsigned short* __restrict__ Aproj,  // [51200][768]
                            const unsigned short* __restrict__ Bfwe,   // [51200][768]
                            const int* __restrict__ fix_seq,           // [256][200]
                            const unsigned char* __restrict__ wmask,   // [51200]
                            float* __restrict__ out) {
    __shared__ unsigned short As[64 * 32];
    __shared__ unsigned short Bs[64 * 32];
    const int blk = blockIdx.x;
    const int b = blk >> 4;
    const int mt = (blk >> 2) & 3;
    const int ntile = blk & 3;
    const int t0 = mt << 6;
    const int w0 = ntile << 6;
    const int tid = threadIdx.x;
    const int lane = tid & 63;
    const int wave = tid >> 6;
    const int wm = (wave >> 1) << 5;
    const int wn = (wave & 1) << 5;

    const int srow = tid >> 2;
    const int sbyte = (tid & 3) << 4;
    const int tA = t0 + srow > 199 ? 199 : t0 + srow;   // clamp OOB rows (masked later)
    const int wB = w0 + srow > 199 ? 199 : w0 + srow;
    const char* ga = (const char*)(Aproj + ((long)b * NT + tA) * NE) + sbyte;
    const char* gb = (const char*)(Bfwe + ((long)b * NW + wB) * NE) + sbyte;
    char* la = (char*)As + srow * 64 + sbyte;
    char* lb = (char*)Bs + srow * 64 + sbyte;

    f32x4 acc[2][2] = {};
    bf16x8 ra = *(const bf16x8*)(ga);
    bf16x8 rb = *(const bf16x8*)(gb);
    for (int kt = 0; kt < 24; kt++) {
        __syncthreads();
        *(bf16x8*)(la) = ra;
        *(bf16x8*)(lb) = rb;
        __syncthreads();
        if (kt < 23) {
            ra = *(const bf16x8*)(ga + (kt + 1) * 64);
            rb = *(const bf16x8*)(gb + (kt + 1) * 64);
        }
        bf16x8 af[2], bfr[2];
        #pragma unroll
        for (int mi = 0; mi < 2; mi++)
            af[mi] = *(const bf16x8*)((const char*)As +
                        (wm + mi * 16 + (lane & 15)) * 64 + ((lane >> 4) << 4));
        #pragma unroll
        for (int ni = 0; ni < 2; ni++)
            bfr[ni] = *(const bf16x8*)((const char*)Bs +
                        (wn + ni * 16 + (lane & 15)) * 64 + ((lane >> 4) << 4));
        #pragma unroll
        for (int mi = 0; mi < 2; mi++)
            #pragma unroll
            for (int ni = 0; ni < 2; ni++)
                acc[mi][ni] = __builtin_amdgcn_mfma_f32_16x16x32_bf16(
                                  af[mi], bfr[ni], acc[mi][ni], 0, 0, 0);
    }
    // epilogue with saccade-window + valid + word masks
    #pragma unroll
    for (int mi = 0; mi < 2; mi++) {
        #pragma unroll
        for (int r = 0; r < 4; r++) {
            const int t = t0 + wm + mi * 16 + ((lane >> 4) << 2) + r;
            if (t >= NT) continue;
            const int fx = fix_seq[b * NT + t];
            #pragma unroll
            for (int ni = 0; ni < 2; ni++) {
                const int w = w0 + wn + ni * 16 + (lane & 15);
                if (w >= NW) continue;
                int d = w - fx; d = d < 0 ? -d : d;
                const bool ok = (fx != 0) && (d <= 8) && (wmask[b * NW + w] != 0);
                out[(long)b * (NT * NW) + t * NW + w] = ok ? acc[mi][ni][r] : -1e9f;
            }
        }
    }
}

// ---------------------------------------------------------------------------
// dur_kernel: dur[b,t] = dot(hout[b,t,:], W_dur) + b_dur. One wave per row.
// ---------------------------------------------------------------------------
__global__ void dur_kernel(const unsigned short* __restrict__ hout,
                           const float* __restrict__ Wdur, const float* __restrict__ bdur,
                           float* __restrict__ out) {
    const int row = (int)((blockIdx.x * blockDim.x + threadIdx.x) >> 6);
    const int lane = threadIdx.x & 63;
    if (row >= MROWS) return;
    const unsigned short* hp = hout + (long)row * NH + lane * 4;
    const uint2 hv = *(const uint2*)hp;
    const float4 wv = *(const float4*)(Wdur + lane * 4);
    float s = bf2f((unsigned short)(hv.x & 0xffff)) * wv.x
            + bf2f((unsigned short)(hv.x >> 16)) * wv.y
            + bf2f((unsigned short)(hv.y & 0xffff)) * wv.z
            + bf2f((unsigned short)(hv.y >> 16)) * wv.w;
    #pragma unroll
    for (int off = 32; off >= 1; off >>= 1) s += __shfl_down(s, off);
    if (lane == 0) out[(long)NB * NT * NW + row] = s + bdur[0];
}

// ---------------------------------------------------------------------------
extern "C" void kernel_launch(void* const* d_in, const int* in_sizes, int n_in,
                              void* d_out, int out_size, void* d_ws, size_t ws_size,
                              hipStream_t stream) {
    (void)in_sizes; (void)n_in; (void)out_size; (void)ws_size;
    const float* inputs  = (const float*)d_in[0];
    const int*   fix_seq = (const int*)d_in[1];
    const float* fwe     = (const float*)d_in[2];
    const int*   lengths = (const int*)d_in[3];
    const float* emb     = (const float*)d_in[5];
    const float* Wih     = (const float*)d_in[6];
    const float* bih     = (const float*)d_in[7];
    const float* Whh     = (const float*)d_in[8];
    const float* bhh     = (const float*)d_in[9];
    const float* Wout    = (const float*)d_in[10];
    const float* bout    = (const float*)d_in[11];
    const float* Wdur    = (const float*)d_in[12];
    const float* bdur    = (const float*)d_in[13];
    float* out = (float*)d_out;

    char* ws = (char*)d_ws;
    // region layout (bytes, all 256-aligned):
    //   [0, 81,920,000)            A_bf16 [51200][800]    -> reused as proj_bf16
    //   [81,920,000, +78,643,200)  xg_bf16 [51200][768]   -> reused as fwe_bf16
    //   [160,563,200, +26,214,400) hout_bf16 [51200][256]
    //   [186,777,600, +1,228,800)  W_ih bf16
    //   [188,006,400, +393,216)    W_out bf16
    //   [188,399,616, +51,200)     word_mask u8
    unsigned short* Abf    = (unsigned short*)(ws);
    unsigned short* xgbf   = (unsigned short*)(ws + 81920000);
    unsigned short* hout   = (unsigned short*)(ws + 160563200);
    unsigned short* Wihbf  = (unsigned short*)(ws + 186777600);
    unsigned short* Woutbf = (unsigned short*)(ws + 188006400);
    unsigned char*  wmask  = (unsigned char*)(ws + 188399616);
    unsigned short* projbf = Abf;    // A dead after gemm1
    unsigned short* fwebf  = xgbf;   // xg dead after scan

    prep1<<<2048, 256, 0, stream>>>(inputs, fix_seq, emb, Wih, Wout, Abf, Wihbf, Woutbf);
    gemm_bt128<<<400 * 6, 256, 0, stream>>>(Abf, Wihbf, bih, xgbf, MROWS, G3H, KIN);
    gru_scan<<<256, 512, 0, stream>>>(xgbf, Whh, bhh, lengths, hout);
    gemm_bt128<<<400 * 6, 256, 0, stream>>>(hout, Woutbf, bout, projbf, MROWS, G3H, NH);
    prep2<<<12800, 256, 0, stream>>>(fwe, fwebf, wmask);
    logits_gemm<<<4096, 256, 0, stream>>>(projbf, fwebf, fix_seq, wmask, out);
    dur_kernel<<<12800, 256, 0, stream>>>(hout, Wdur, bdur, out);
}

// Round 4
// 695.547 us; speedup vs baseline: 1.8265x; 1.2802x over previous
//
#include <hip/hip_runtime.h>
#include <hip/hip_bf16.h>

typedef __attribute__((ext_vector_type(8))) short bf16x8;   // 8 bf16 in 4 VGPRs
typedef __attribute__((ext_vector_type(4))) float f32x4;    // MFMA accumulator

#define NB 256
#define NT 200
#define NW 200
#define NE 768
#define NH 256
#define NEMB 32
#define KIN 800           // E + EMB
#define G3H 768           // 3*H
#define MROWS 51200       // B*T

__device__ __forceinline__ float bf2f(unsigned short h) {
    return __uint_as_float(((unsigned)h) << 16);
}
__device__ __forceinline__ unsigned short f2bf(float f) {
    unsigned u = __float_as_uint(f);
    u += 0x7fff + ((u >> 16) & 1);   // RNE
    return (unsigned short)(u >> 16);
}
__device__ __forceinline__ float sigm(float x) { return 1.0f / (1.0f + __expf(-x)); }
__device__ __forceinline__ float tanh_fast(float x) {
    float e = __expf(2.0f * x);
    return 1.0f - 2.0f / (e + 1.0f);
}

// ---------------------------------------------------------------------------
// prep1: A_bf16[51200][800] = [bf16(inputs) | bf16(emb_table[fix])],
//        W_ih -> bf16 [768][800], W_out -> bf16 [768][256],
//        biasC[768] = b_ih + (row<512 ? b_hh : 0)   (b_hh r,z folded into xg)
// ---------------------------------------------------------------------------
__global__ void prep1(const float* __restrict__ inputs, const int* __restrict__ fix_seq,
                      const float* __restrict__ emb, const float* __restrict__ Wih,
                      const float* __restrict__ Wout, const float* __restrict__ bih,
                      const float* __restrict__ bhh,
                      unsigned short* __restrict__ Abf, unsigned short* __restrict__ Wihbf,
                      unsigned short* __restrict__ Woutbf, float* __restrict__ biasC) {
    const long gid0 = (long)blockIdx.x * blockDim.x + threadIdx.x;
    if (gid0 < G3H) biasC[gid0] = bih[gid0] + (gid0 < 512 ? bhh[gid0] : 0.0f);
    const long NA = (long)MROWS * 100;   // 8 cols per unit
    const long NWU = 768L * 100;
    const long NOU = 768L * 32;
    const long total = NA + NWU + NOU;
    for (long u = gid0; u < total; u += (long)gridDim.x * blockDim.x) {
        bf16x8 v;
        unsigned short* dst;
        if (u < NA) {
            long row = u / 100;
            int c8 = (int)(u % 100) * 8;
            const float* s;
            if (c8 < NE) {
                s = inputs + row * NE + c8;
            } else {
                int fx = fix_seq[row];
                s = emb + (long)fx * NEMB + (c8 - NE);
            }
            #pragma unroll
            for (int j = 0; j < 8; j++) v[j] = (short)f2bf(s[j]);
            dst = Abf + row * KIN + c8;
        } else if (u < NA + NWU) {
            long u2 = u - NA;
            long row = u2 / 100;
            int c8 = (int)(u2 % 100) * 8;
            const float* s = Wih + row * KIN + c8;
            #pragma unroll
            for (int j = 0; j < 8; j++) v[j] = (short)f2bf(s[j]);
            dst = Wihbf + row * KIN + c8;
        } else {
            long u3 = u - NA - NWU;
            long row = u3 / 32;
            int c8 = (int)(u3 % 32) * 8;
            const float* s = Wout + row * NH + c8;
            #pragma unroll
            for (int j = 0; j < 8; j++) v[j] = (short)f2bf(s[j]);
            dst = Woutbf + row * NH + c8;
        }
        *(bf16x8*)dst = v;
    }
}

// ---------------------------------------------------------------------------
// gemm_bt128: Out[M][N] (bf16) = A[M][K](bf16) * Bw[N][K](bf16)^T + bias
// BM=BN=128, BK=32, 256 threads (4 waves, each 64x64). Reg-staged LDS tiles.
// ---------------------------------------------------------------------------
__global__ void gemm_bt128(const unsigned short* __restrict__ A,
                           const unsigned short* __restrict__ Bw,
                           const float* __restrict__ bias,
                           unsigned short* __restrict__ Out,
                           int M, int N, int K) {
    __shared__ unsigned short As[128 * 32];
    __shared__ unsigned short Bs[128 * 32];
    const int nblk = N >> 7;
    const int m0 = (blockIdx.x / nblk) << 7;
    const int n0 = (blockIdx.x % nblk) << 7;
    const int tid = threadIdx.x;
    const int lane = tid & 63;
    const int wave = tid >> 6;
    const int wm = (wave >> 1) << 6;
    const int wn = (wave & 1) << 6;
    const int nk = K >> 5;

    const int srow = tid >> 1;
    const int sbyte = (tid & 1) << 5;
    const char* ga = (const char*)(A + (long)(m0 + srow) * K) + sbyte;
    const char* gb = (const char*)(Bw + (long)(n0 + srow) * K) + sbyte;
    char* la = (char*)As + srow * 64 + sbyte;
    char* lb = (char*)Bs + srow * 64 + sbyte;

    f32x4 acc[4][4] = {};

    bf16x8 ra0 = *(const bf16x8*)(ga);
    bf16x8 ra1 = *(const bf16x8*)(ga + 16);
    bf16x8 rb0 = *(const bf16x8*)(gb);
    bf16x8 rb1 = *(const bf16x8*)(gb + 16);

    for (int kt = 0; kt < nk; kt++) {
        __syncthreads();
        *(bf16x8*)(la) = ra0;      *(bf16x8*)(la + 16) = ra1;
        *(bf16x8*)(lb) = rb0;      *(bf16x8*)(lb + 16) = rb1;
        __syncthreads();
        if (kt + 1 < nk) {  // prefetch next tile into regs; latency hides under MFMA
            const char* pa = ga + (kt + 1) * 64;
            const char* pb = gb + (kt + 1) * 64;
            ra0 = *(const bf16x8*)(pa);      ra1 = *(const bf16x8*)(pa + 16);
            rb0 = *(const bf16x8*)(pb);      rb1 = *(const bf16x8*)(pb + 16);
        }
        bf16x8 af[4], bfr[4];
        #pragma unroll
        for (int mi = 0; mi < 4; mi++)
            af[mi] = *(const bf16x8*)((const char*)As +
                        (wm + mi * 16 + (lane & 15)) * 64 + ((lane >> 4) << 4));
        #pragma unroll
        for (int ni = 0; ni < 4; ni++)
            bfr[ni] = *(const bf16x8*)((const char*)Bs +
                        (wn + ni * 16 + (lane & 15)) * 64 + ((lane >> 4) << 4));
        #pragma unroll
        for (int mi = 0; mi < 4; mi++)
            #pragma unroll
            for (int ni = 0; ni < 4; ni++)
                acc[mi][ni] = __builtin_amdgcn_mfma_f32_16x16x32_bf16(
                                  af[mi], bfr[ni], acc[mi][ni], 0, 0, 0);
    }
    // epilogue: D col = lane&15, row = (lane>>4)*4 + r  (m89-verified layout)
    #pragma unroll
    for (int ni = 0; ni < 4; ni++) {
        const int col = n0 + wn + ni * 16 + (lane & 15);
        const float bv = bias[col];
        #pragma unroll
        for (int mi = 0; mi < 4; mi++) {
            const int row = m0 + wm + mi * 16 + ((lane >> 4) << 2);
            #pragma unroll
            for (int r = 0; r < 4; r++)
                Out[(long)(row + r) * N + col] = f2bf(acc[mi][ni][r] + bv);
        }
    }
}

// ---------------------------------------------------------------------------
// gru_scan: 256 blocks (1 batch each), 1024 threads (16 waves, 4/SIMD).
// Wave w owns 16 h-cols [16w,16w+16): per-thread resident W_hh = 384 B = 96
// VGPR (fits the 128-VGPR cap at 4 waves/SIMD -> no spill, no remat).
// Lanes 0-15 get r,z,n for their own col in acc[g][0] -> lane-local gates.
// All lanes read the same LDS A-frag address per 16-lane group (broadcast;
// garbage contributes only to unread D rows 1-15). b_hh for r,z folded into
// xg bias; only n-gate b_hh kept (1 reg). Barrier = lgkmcnt-only.
// ---------------------------------------------------------------------------
__global__ __launch_bounds__(1024)
void gru_scan(const unsigned short* __restrict__ xg,   // [51200][768] bf16 (incl biasC)
              const float* __restrict__ Whh,            // [768][256] fp32
              const float* __restrict__ bhh,            // [768]
              const int* __restrict__ lengths,          // [256]
              unsigned short* __restrict__ hout) {      // [51200][256] bf16 (masked)
    __shared__ unsigned short hbf[2][256];   // h double buffer, 512 B each
    const int tid = threadIdx.x;
    const int lane = tid & 63;
    const int wave = tid >> 6;               // 0..15
    const int b = blockIdx.x;
    const int l = lane & 15;
    const int sub = lane >> 4;               // k-subslice 0..3
    const int c = wave * 16 + l;             // this lane's h-col

    // resident W_hh B-frags: gate g -> row g*256 + c, k = kt*32 + sub*8 .. +8
    bf16x8 wf[3][8];
    #pragma unroll
    for (int g = 0; g < 3; g++) {
        const int nrow = g * 256 + c;
        #pragma unroll
        for (int kt = 0; kt < 8; kt++) {
            const float4 f0 = *(const float4*)(Whh + (long)nrow * NH + kt * 32 + sub * 8);
            const float4 f1 = *(const float4*)(Whh + (long)nrow * NH + kt * 32 + sub * 8 + 4);
            bf16x8 v;
            v[0] = (short)f2bf(f0.x); v[1] = (short)f2bf(f0.y);
            v[2] = (short)f2bf(f0.z); v[3] = (short)f2bf(f0.w);
            v[4] = (short)f2bf(f1.x); v[5] = (short)f2bf(f1.y);
            v[6] = (short)f2bf(f1.z); v[7] = (short)f2bf(f1.w);
            wf[g][kt] = v;
        }
    }
    const float bhn = bhh[512 + c];          // n-gate b_hh (r,z folded into xg)
    const int len = lengths[b];
    if (tid < 256) ((unsigned*)hbf)[tid] = 0u;   // zero both h buffers

    const unsigned short* xrow = xg + (long)b * NT * G3H;
    const bool gl = (lane < 16);
    unsigned short xv0 = 0, xv1 = 0, xv2 = 0;
    if (gl) { xv0 = xrow[c]; xv1 = xrow[256 + c]; xv2 = xrow[512 + c]; }
    float hp = 0.0f;

    asm volatile("s_waitcnt lgkmcnt(0)" ::: "memory");
    __builtin_amdgcn_sched_barrier(0);
    __builtin_amdgcn_s_barrier();
    __builtin_amdgcn_sched_barrier(0);

    for (int t = 0; t < NT; t++) {
        // hg = h_{t-1} @ Whh^T for this wave's 16 cols x 3 gates
        const char* hb = (const char*)(hbf[(t + 1) & 1]);
        f32x4 acc0 = {}, acc1 = {}, acc2 = {};
        #pragma unroll
        for (int kt = 0; kt < 8; kt++) {
            const bf16x8 af = *(const bf16x8*)(hb + kt * 64 + (sub << 4));
            acc0 = __builtin_amdgcn_mfma_f32_16x16x32_bf16(af, wf[0][kt], acc0, 0, 0, 0);
            acc1 = __builtin_amdgcn_mfma_f32_16x16x32_bf16(af, wf[1][kt], acc1, 0, 0, 0);
            acc2 = __builtin_amdgcn_mfma_f32_16x16x32_bf16(af, wf[2][kt], acc2, 0, 0, 0);
        }
        if (gl) {
            const float r = sigm(bf2f(xv0) + acc0[0]);
            const float z = sigm(bf2f(xv1) + acc1[0]);
            const float n = tanh_fast(bf2f(xv2) + r * (acc2[0] + bhn));
            hp = (1.0f - z) * n + z * hp;
            const unsigned short hv = f2bf(hp);
            hbf[t & 1][c] = hv;
            hout[((long)b * NT + t) * NH + c] = (t < len) ? hv : (unsigned short)0;
            if (t + 1 < NT) {                 // prefetch next step's xg (floats past barrier)
                const unsigned short* xn = xrow + (long)(t + 1) * G3H;
                xv0 = xn[c]; xv1 = xn[256 + c]; xv2 = xn[512 + c];
            }
        }
        // LDS-only baton: no vmcnt drain (hout stores + xg prefetch stay in flight)
        asm volatile("s_waitcnt lgkmcnt(0)" ::: "memory");
        __builtin_amdgcn_sched_barrier(0);
        __builtin_amdgcn_s_barrier();
        __builtin_amdgcn_sched_barrier(0);
    }
}

// ---------------------------------------------------------------------------
// prep2: fwe fp32 -> bf16 + word_mask (sum|row| != 0). One wave per row.
// ---------------------------------------------------------------------------
__global__ void prep2(const float* __restrict__ fwe, unsigned short* __restrict__ fwebf,
                      unsigned char* __restrict__ wmask) {
    const int row = (int)((blockIdx.x * blockDim.x + threadIdx.x) >> 6);
    const int lane = threadIdx.x & 63;
    if (row >= MROWS) return;
    const float* s = fwe + (long)row * NE;
    unsigned short* d = fwebf + (long)row * NE;
    float asum = 0.0f;
    #pragma unroll
    for (int i = 0; i < 12; i++) {
        const float v = s[lane + i * 64];
        asum += fabsf(v);
        d[lane + i * 64] = f2bf(v);
    }
    #pragma unroll
    for (int off = 32; off >= 1; off >>= 1) asum += __shfl_xor(asum, off);
    if (lane == 0) wmask[row] = (asum != 0.0f) ? 1 : 0;
}

// ---------------------------------------------------------------------------
// logits_gemm: per-batch GEMM [200 x 768] x [200 x 768]^T with mask epilogue.
// ---------------------------------------------------------------------------
__global__ void logits_gemm(const unsigned short* __restrict__ Aproj,  // [51200][768]
                            const unsigned short* __restrict__ Bfwe,   // [51200][768]
                            const int* __restrict__ fix_seq,           // [256][200]
                            const unsigned char* __restrict__ wmask,   // [51200]
                            float* __restrict__ out) {
    __shared__ unsigned short As[64 * 32];
    __shared__ unsigned short Bs[64 * 32];
    const int blk = blockIdx.x;
    const int b = blk >> 4;
    const int mt = (blk >> 2) & 3;
    const int ntile = blk & 3;
    const int t0 = mt << 6;
    const int w0 = ntile << 6;
    const int tid = threadIdx.x;
    const int lane = tid & 63;
    const int wave = tid >> 6;
    const int wm = (wave >> 1) << 5;
    const int wn = (wave & 1) << 5;

    const int srow = tid >> 2;
    const int sbyte = (tid & 3) << 4;
    const int tA = t0 + srow > 199 ? 199 : t0 + srow;   // clamp OOB rows (masked later)
    const int wB = w0 + srow > 199 ? 199 : w0 + srow;
    const char* ga = (const char*)(Aproj + ((long)b * NT + tA) * NE) + sbyte;
    const char* gb = (const char*)(Bfwe + ((long)b * NW + wB) * NE) + sbyte;
    char* la = (char*)As + srow * 64 + sbyte;
    char* lb = (char*)Bs + srow * 64 + sbyte;

    f32x4 acc[2][2] = {};
    bf16x8 ra = *(const bf16x8*)(ga);
    bf16x8 rb = *(const bf16x8*)(gb);
    for (int kt = 0; kt < 24; kt++) {
        __syncthreads();
        *(bf16x8*)(la) = ra;
        *(bf16x8*)(lb) = rb;
        __syncthreads();
        if (kt < 23) {
            ra = *(const bf16x8*)(ga + (kt + 1) * 64);
            rb = *(const bf16x8*)(gb + (kt + 1) * 64);
        }
        bf16x8 af[2], bfr[2];
        #pragma unroll
        for (int mi = 0; mi < 2; mi++)
            af[mi] = *(const bf16x8*)((const char*)As +
                        (wm + mi * 16 + (lane & 15)) * 64 + ((lane >> 4) << 4));
        #pragma unroll
        for (int ni = 0; ni < 2; ni++)
            bfr[ni] = *(const bf16x8*)((const char*)Bs +
                        (wn + ni * 16 + (lane & 15)) * 64 + ((lane >> 4) << 4));
        #pragma unroll
        for (int mi = 0; mi < 2; mi++)
            #pragma unroll
            for (int ni = 0; ni < 2; ni++)
                acc[mi][ni] = __builtin_amdgcn_mfma_f32_16x16x32_bf16(
                                  af[mi], bfr[ni], acc[mi][ni], 0, 0, 0);
    }
    // epilogue with saccade-window + valid + word masks
    #pragma unroll
    for (int mi = 0; mi < 2; mi++) {
        #pragma unroll
        for (int r = 0; r < 4; r++) {
            const int t = t0 + wm + mi * 16 + ((lane >> 4) << 2) + r;
            if (t >= NT) continue;
            const int fx = fix_seq[b * NT + t];
            #pragma unroll
            for (int ni = 0; ni < 2; ni++) {
                const int w = w0 + wn + ni * 16 + (lane & 15);
                if (w >= NW) continue;
                int d = w - fx; d = d < 0 ? -d : d;
                const bool ok = (fx != 0) && (d <= 8) && (wmask[b * NW + w] != 0);
                out[(long)b * (NT * NW) + t * NW + w] = ok ? acc[mi][ni][r] : -1e9f;
            }
        }
    }
}

// ---------------------------------------------------------------------------
// dur_kernel: dur[b,t] = dot(hout[b,t,:], W_dur) + b_dur. One wave per row.
// ---------------------------------------------------------------------------
__global__ void dur_kernel(const unsigned short* __restrict__ hout,
                           const float* __restrict__ Wdur, const float* __restrict__ bdur,
                           float* __restrict__ out) {
    const int row = (int)((blockIdx.x * blockDim.x + threadIdx.x) >> 6);
    const int lane = threadIdx.x & 63;
    if (row >= MROWS) return;
    const unsigned short* hp = hout + (long)row * NH + lane * 4;
    const uint2 hv = *(const uint2*)hp;
    const float4 wv = *(const float4*)(Wdur + lane * 4);
    float s = bf2f((unsigned short)(hv.x & 0xffff)) * wv.x
            + bf2f((unsigned short)(hv.x >> 16)) * wv.y
            + bf2f((unsigned short)(hv.y & 0xffff)) * wv.z
            + bf2f((unsigned short)(hv.y >> 16)) * wv.w;
    #pragma unroll
    for (int off = 32; off >= 1; off >>= 1) s += __shfl_down(s, off);
    if (lane == 0) out[(long)NB * NT * NW + row] = s + bdur[0];
}

// ---------------------------------------------------------------------------
extern "C" void kernel_launch(void* const* d_in, const int* in_sizes, int n_in,
                              void* d_out, int out_size, void* d_ws, size_t ws_size,
                              hipStream_t stream) {
    (void)in_sizes; (void)n_in; (void)out_size; (void)ws_size;
    const float* inputs  = (const float*)d_in[0];
    const int*   fix_seq = (const int*)d_in[1];
    const float* fwe     = (const float*)d_in[2];
    const int*   lengths = (const int*)d_in[3];
    const float* emb     = (const float*)d_in[5];
    const float* Wih     = (const float*)d_in[6];
    const float* bih     = (const float*)d_in[7];
    const float* Whh     = (const float*)d_in[8];
    const float* bhh     = (const float*)d_in[9];
    const float* Wout    = (const float*)d_in[10];
    const float* bout    = (const float*)d_in[11];
    const float* Wdur    = (const float*)d_in[12];
    const float* bdur    = (const float*)d_in[13];
    float* out = (float*)d_out;

    char* ws = (char*)d_ws;
    // region layout (bytes, all 256-aligned):
    //   [0, 81,920,000)            A_bf16 [51200][800]    -> reused as proj_bf16
    //   [81,920,000, +78,643,200)  xg_bf16 [51200][768]   -> reused as fwe_bf16
    //   [160,563,200, +26,214,400) hout_bf16 [51200][256]
    //   [186,777,600, +1,228,800)  W_ih bf16
    //   [188,006,400, +393,216)    W_out bf16
    //   [188,399,616, +51,200)     word_mask u8
    //   [188,450,816, +3,072)      biasC f32 [768]
    unsigned short* Abf    = (unsigned short*)(ws);
    unsigned short* xgbf   = (unsigned short*)(ws + 81920000);
    unsigned short* hout   = (unsigned short*)(ws + 160563200);
    unsigned short* Wihbf  = (unsigned short*)(ws + 186777600);
    unsigned short* Woutbf = (unsigned short*)(ws + 188006400);
    unsigned char*  wmask  = (unsigned char*)(ws + 188399616);
    float*          biasC  = (float*)(ws + 188450816);
    unsigned short* projbf = Abf;    // A dead after gemm1
    unsigned short* fwebf  = xgbf;   // xg dead after scan

    prep1<<<2048, 256, 0, stream>>>(inputs, fix_seq, emb, Wih, Wout, bih, bhh,
                                    Abf, Wihbf, Woutbf, biasC);
    gemm_bt128<<<400 * 6, 256, 0, stream>>>(Abf, Wihbf, biasC, xgbf, MROWS, G3H, KIN);
    gru_scan<<<256, 1024, 0, stream>>>(xgbf, Whh, bhh, lengths, hout);
    gemm_bt128<<<400 * 6, 256, 0, stream>>>(hout, Woutbf, bout, projbf, MROWS, G3H, NH);
    prep2<<<12800, 256, 0, stream>>>(fwe, fwebf, wmask);
    logits_gemm<<<4096, 256, 0, stream>>>(projbf, fwebf, fix_seq, wmask, out);
    dur_kernel<<<12800, 256, 0, stream>>>(hout, Wdur, bdur, out);
}

// Round 5
// 694.532 us; speedup vs baseline: 1.8291x; 1.0015x over previous
//
#include <hip/hip_runtime.h>
#include <hip/hip_bf16.h>

typedef __attribute__((ext_vector_type(8))) short bf16x8;   // 8 bf16 in 4 VGPRs
typedef __attribute__((ext_vector_type(4))) float f32x4;    // MFMA accumulator

#define NB 256
#define NT 200
#define NW 200
#define NE 768
#define NH 256
#define NEMB 32
#define KIN 800           // E + EMB
#define G3H 768           // 3*H
#define MROWS 51200       // B*T

__device__ __forceinline__ float bf2f(unsigned short h) {
    return __uint_as_float(((unsigned)h) << 16);
}
__device__ __forceinline__ unsigned short f2bf(float f) {
    unsigned u = __float_as_uint(f);
    u += 0x7fff + ((u >> 16) & 1);   // RNE
    return (unsigned short)(u >> 16);
}
__device__ __forceinline__ float sigm(float x) { return 1.0f / (1.0f + __expf(-x)); }
__device__ __forceinline__ float tanh_fast(float x) {
    float e = __expf(2.0f * x);
    return 1.0f - 2.0f / (e + 1.0f);
}

// ---------------------------------------------------------------------------
// prep1: A_bf16[51200][800] = [bf16(inputs) | bf16(emb_table[fix])],
//        W_ih -> bf16 [768][800], W_out -> bf16 [768][256],
//        biasC[768] = b_ih + (row<512 ? b_hh : 0)   (b_hh r,z folded into xg)
// ---------------------------------------------------------------------------
__global__ void prep1(const float* __restrict__ inputs, const int* __restrict__ fix_seq,
                      const float* __restrict__ emb, const float* __restrict__ Wih,
                      const float* __restrict__ Wout, const float* __restrict__ bih,
                      const float* __restrict__ bhh,
                      unsigned short* __restrict__ Abf, unsigned short* __restrict__ Wihbf,
                      unsigned short* __restrict__ Woutbf, float* __restrict__ biasC) {
    const long gid0 = (long)blockIdx.x * blockDim.x + threadIdx.x;
    if (gid0 < G3H) biasC[gid0] = bih[gid0] + (gid0 < 512 ? bhh[gid0] : 0.0f);
    const long NA = (long)MROWS * 100;   // 8 cols per unit
    const long NWU = 768L * 100;
    const long NOU = 768L * 32;
    const long total = NA + NWU + NOU;
    for (long u = gid0; u < total; u += (long)gridDim.x * blockDim.x) {
        bf16x8 v;
        unsigned short* dst;
        if (u < NA) {
            long row = u / 100;
            int c8 = (int)(u % 100) * 8;
            const float* s;
            if (c8 < NE) {
                s = inputs + row * NE + c8;
            } else {
                int fx = fix_seq[row];
                s = emb + (long)fx * NEMB + (c8 - NE);
            }
            #pragma unroll
            for (int j = 0; j < 8; j++) v[j] = (short)f2bf(s[j]);
            dst = Abf + row * KIN + c8;
        } else if (u < NA + NWU) {
            long u2 = u - NA;
            long row = u2 / 100;
            int c8 = (int)(u2 % 100) * 8;
            const float* s = Wih + row * KIN + c8;
            #pragma unroll
            for (int j = 0; j < 8; j++) v[j] = (short)f2bf(s[j]);
            dst = Wihbf + row * KIN + c8;
        } else {
            long u3 = u - NA - NWU;
            long row = u3 / 32;
            int c8 = (int)(u3 % 32) * 8;
            const float* s = Wout + row * NH + c8;
            #pragma unroll
            for (int j = 0; j < 8; j++) v[j] = (short)f2bf(s[j]);
            dst = Woutbf + row * NH + c8;
        }
        *(bf16x8*)dst = v;
    }
}

// ---------------------------------------------------------------------------
// gemm_bt128: Out[M][N] (bf16) = A[M][K](bf16) * Bw[N][K](bf16)^T + bias
// BM=BN=128, BK=32, 256 threads (4 waves, each 64x64). Reg-staged LDS tiles.
// ---------------------------------------------------------------------------
__global__ void gemm_bt128(const unsigned short* __restrict__ A,
                           const unsigned short* __restrict__ Bw,
                           const float* __restrict__ bias,
                           unsigned short* __restrict__ Out,
                           int M, int N, int K) {
    __shared__ unsigned short As[128 * 32];
    __shared__ unsigned short Bs[128 * 32];
    const int nblk = N >> 7;
    const int m0 = (blockIdx.x / nblk) << 7;
    const int n0 = (blockIdx.x % nblk) << 7;
    const int tid = threadIdx.x;
    const int lane = tid & 63;
    const int wave = tid >> 6;
    const int wm = (wave >> 1) << 6;
    const int wn = (wave & 1) << 6;
    const int nk = K >> 5;

    const int srow = tid >> 1;
    const int sbyte = (tid & 1) << 5;
    const char* ga = (const char*)(A + (long)(m0 + srow) * K) + sbyte;
    const char* gb = (const char*)(Bw + (long)(n0 + srow) * K) + sbyte;
    char* la = (char*)As + srow * 64 + sbyte;
    char* lb = (char*)Bs + srow * 64 + sbyte;

    f32x4 acc[4][4] = {};

    bf16x8 ra0 = *(const bf16x8*)(ga);
    bf16x8 ra1 = *(const bf16x8*)(ga + 16);
    bf16x8 rb0 = *(const bf16x8*)(gb);
    bf16x8 rb1 = *(const bf16x8*)(gb + 16);

    for (int kt = 0; kt < nk; kt++) {
        __syncthreads();
        *(bf16x8*)(la) = ra0;      *(bf16x8*)(la + 16) = ra1;
        *(bf16x8*)(lb) = rb0;      *(bf16x8*)(lb + 16) = rb1;
        __syncthreads();
        if (kt + 1 < nk) {  // prefetch next tile into regs; latency hides under MFMA
            const char* pa = ga + (kt + 1) * 64;
            const char* pb = gb + (kt + 1) * 64;
            ra0 = *(const bf16x8*)(pa);      ra1 = *(const bf16x8*)(pa + 16);
            rb0 = *(const bf16x8*)(pb);      rb1 = *(const bf16x8*)(pb + 16);
        }
        bf16x8 af[4], bfr[4];
        #pragma unroll
        for (int mi = 0; mi < 4; mi++)
            af[mi] = *(const bf16x8*)((const char*)As +
                        (wm + mi * 16 + (lane & 15)) * 64 + ((lane >> 4) << 4));
        #pragma unroll
        for (int ni = 0; ni < 4; ni++)
            bfr[ni] = *(const bf16x8*)((const char*)Bs +
                        (wn + ni * 16 + (lane & 15)) * 64 + ((lane >> 4) << 4));
        #pragma unroll
        for (int mi = 0; mi < 4; mi++)
            #pragma unroll
            for (int ni = 0; ni < 4; ni++)
                acc[mi][ni] = __builtin_amdgcn_mfma_f32_16x16x32_bf16(
                                  af[mi], bfr[ni], acc[mi][ni], 0, 0, 0);
    }
    // epilogue: D col = lane&15, row = (lane>>4)*4 + r  (m89-verified layout)
    #pragma unroll
    for (int ni = 0; ni < 4; ni++) {
        const int col = n0 + wn + ni * 16 + (lane & 15);
        const float bv = bias[col];
        #pragma unroll
        for (int mi = 0; mi < 4; mi++) {
            const int row = m0 + wm + mi * 16 + ((lane >> 4) << 2);
            #pragma unroll
            for (int r = 0; r < 4; r++)
                Out[(long)(row + r) * N + col] = f2bf(acc[mi][ni][r] + bv);
        }
    }
}

// ---------------------------------------------------------------------------
// gru_scan: 256 blocks (1 batch each), 1024 threads (16 waves, 4/SIMD).
// Wave w owns 16 h-cols [16w,16w+16): per-thread resident W_hh = 384 B = 96
// VGPR. amdgpu_waves_per_eu(4,4) pins the allocator to the 128-VGPR budget
// (R4 evidence: without it the allocator chose 64 regs / 2 blocks/CU and
// spilled wf -> 160 MB of scratch traffic, WRITE_SIZE 185 MB).
// Lanes 0-15 get r,z,n for their own col in acc[g][0] -> lane-local gates.
// b_hh for r,z folded into xg bias; only n-gate b_hh kept (1 reg).
// Barrier = lgkmcnt-only (hout stores + xg prefetch stay in flight).
// ---------------------------------------------------------------------------
__global__ __launch_bounds__(1024)
__attribute__((amdgpu_waves_per_eu(4, 4)))
void gru_scan(const unsigned short* __restrict__ xg,   // [51200][768] bf16 (incl biasC)
              const float* __restrict__ Whh,            // [768][256] fp32
              const float* __restrict__ bhh,            // [768]
              const int* __restrict__ lengths,          // [256]
              unsigned short* __restrict__ hout) {      // [51200][256] bf16 (masked)
    __shared__ unsigned short hbf[2][256];   // h double buffer, 512 B each
    const int tid = threadIdx.x;
    const int lane = tid & 63;
    const int wave = tid >> 6;               // 0..15
    const int b = blockIdx.x;
    const int l = lane & 15;
    const int sub = lane >> 4;               // k-subslice 0..3
    const int c = wave * 16 + l;             // this lane's h-col

    // resident W_hh B-frags: gate g -> row g*256 + c, k = kt*32 + sub*8 .. +8
    bf16x8 wf[3][8];
    #pragma unroll
    for (int g = 0; g < 3; g++) {
        const int nrow = g * 256 + c;
        #pragma unroll
        for (int kt = 0; kt < 8; kt++) {
            const float4 f0 = *(const float4*)(Whh + (long)nrow * NH + kt * 32 + sub * 8);
            const float4 f1 = *(const float4*)(Whh + (long)nrow * NH + kt * 32 + sub * 8 + 4);
            bf16x8 v;
            v[0] = (short)f2bf(f0.x); v[1] = (short)f2bf(f0.y);
            v[2] = (short)f2bf(f0.z); v[3] = (short)f2bf(f0.w);
            v[4] = (short)f2bf(f1.x); v[5] = (short)f2bf(f1.y);
            v[6] = (short)f2bf(f1.z); v[7] = (short)f2bf(f1.w);
            wf[g][kt] = v;
        }
    }
    const float bhn = bhh[512 + c];          // n-gate b_hh (r,z folded into xg)
    const int len = lengths[b];
    if (tid < 256) ((unsigned*)hbf)[tid] = 0u;   // zero both h buffers

    const unsigned short* xrow = xg + (long)b * NT * G3H;
    const bool gl = (lane < 16);
    unsigned short xv0 = 0, xv1 = 0, xv2 = 0;
    if (gl) { xv0 = xrow[c]; xv1 = xrow[256 + c]; xv2 = xrow[512 + c]; }
    float hp = 0.0f;

    asm volatile("s_waitcnt lgkmcnt(0)" ::: "memory");
    __builtin_amdgcn_sched_barrier(0);
    __builtin_amdgcn_s_barrier();
    __builtin_amdgcn_sched_barrier(0);

    for (int t = 0; t < NT; t++) {
        // hg = h_{t-1} @ Whh^T for this wave's 16 cols x 3 gates
        const char* hb = (const char*)(hbf[(t + 1) & 1]);
        f32x4 acc0 = {}, acc1 = {}, acc2 = {};
        #pragma unroll
        for (int kt = 0; kt < 8; kt++) {
            const bf16x8 af = *(const bf16x8*)(hb + kt * 64 + (sub << 4));
            acc0 = __builtin_amdgcn_mfma_f32_16x16x32_bf16(af, wf[0][kt], acc0, 0, 0, 0);
            acc1 = __builtin_amdgcn_mfma_f32_16x16x32_bf16(af, wf[1][kt], acc1, 0, 0, 0);
            acc2 = __builtin_amdgcn_mfma_f32_16x16x32_bf16(af, wf[2][kt], acc2, 0, 0, 0);
        }
        if (gl) {
            const float r = sigm(bf2f(xv0) + acc0[0]);
            const float z = sigm(bf2f(xv1) + acc1[0]);
            const float n = tanh_fast(bf2f(xv2) + r * (acc2[0] + bhn));
            hp = (1.0f - z) * n + z * hp;
            const unsigned short hv = f2bf(hp);
            hbf[t & 1][c] = hv;
            hout[((long)b * NT + t) * NH + c] = (t < len) ? hv : (unsigned short)0;
            if (t + 1 < NT) {                 // prefetch next step's xg (floats past barrier)
                const unsigned short* xn = xrow + (long)(t + 1) * G3H;
                xv0 = xn[c]; xv1 = xn[256 + c]; xv2 = xn[512 + c];
            }
        }
        // LDS-only baton: no vmcnt drain (hout stores + xg prefetch stay in flight)
        asm volatile("s_waitcnt lgkmcnt(0)" ::: "memory");
        __builtin_amdgcn_sched_barrier(0);
        __builtin_amdgcn_s_barrier();
        __builtin_amdgcn_sched_barrier(0);
    }
}

// ---------------------------------------------------------------------------
// prep2: fwe fp32 -> bf16 + word_mask (sum|row| != 0). One wave per row.
// ---------------------------------------------------------------------------
__global__ void prep2(const float* __restrict__ fwe, unsigned short* __restrict__ fwebf,
                      unsigned char* __restrict__ wmask) {
    const int row = (int)((blockIdx.x * blockDim.x + threadIdx.x) >> 6);
    const int lane = threadIdx.x & 63;
    if (row >= MROWS) return;
    const float* s = fwe + (long)row * NE;
    unsigned short* d = fwebf + (long)row * NE;
    float asum = 0.0f;
    #pragma unroll
    for (int i = 0; i < 12; i++) {
        const float v = s[lane + i * 64];
        asum += fabsf(v);
        d[lane + i * 64] = f2bf(v);
    }
    #pragma unroll
    for (int off = 32; off >= 1; off >>= 1) asum += __shfl_xor(asum, off);
    if (lane == 0) wmask[row] = (asum != 0.0f) ? 1 : 0;
}

// ---------------------------------------------------------------------------
// logits_gemm: per-batch GEMM [200 x 768] x [200 x 768]^T with mask epilogue.
// ---------------------------------------------------------------------------
__global__ void logits_gemm(const unsigned short* __restrict__ Aproj,  // [51200][768]
                            const unsigned short* __restrict__ Bfwe,   // [51200][768]
                            const int* __restrict__ fix_seq,           // [256][200]
                            const unsigned char* __restrict__ wmask,   // [51200]
                            float* __restrict__ out) {
    __shared__ unsigned short As[64 * 32];
    __shared__ unsigned short Bs[64 * 32];
    const int blk = blockIdx.x;
    const int b = blk >> 4;
    const int mt = (blk >> 2) & 3;
    const int ntile = blk & 3;
    const int t0 = mt << 6;
    const int w0 = ntile << 6;
    const int tid = threadIdx.x;
    const int lane = tid & 63;
    const int wave = tid >> 6;
    const int wm = (wave >> 1) << 5;
    const int wn = (wave & 1) << 5;

    const int srow = tid >> 2;
    const int sbyte = (tid & 3) << 4;
    const int tA = t0 + srow > 199 ? 199 : t0 + srow;   // clamp OOB rows (masked later)
    const int wB = w0 + srow > 199 ? 199 : w0 + srow;
    const char* ga = (const char*)(Aproj + ((long)b * NT + tA) * NE) + sbyte;
    const char* gb = (const char*)(Bfwe + ((long)b * NW + wB) * NE) + sbyte;
    char* la = (char*)As + srow * 64 + sbyte;
    char* lb = (char*)Bs + srow * 64 + sbyte;

    f32x4 acc[2][2] = {};
    bf16x8 ra = *(const bf16x8*)(ga);
    bf16x8 rb = *(const bf16x8*)(gb);
    for (int kt = 0; kt < 24; kt++) {
        __syncthreads();
        *(bf16x8*)(la) = ra;
        *(bf16x8*)(lb) = rb;
        __syncthreads();
        if (kt < 23) {
            ra = *(const bf16x8*)(ga + (kt + 1) * 64);
            rb = *(const bf16x8*)(gb + (kt + 1) * 64);
        }
        bf16x8 af[2], bfr[2];
        #pragma unroll
        for (int mi = 0; mi < 2; mi++)
            af[mi] = *(const bf16x8*)((const char*)As +
                        (wm + mi * 16 + (lane & 15)) * 64 + ((lane >> 4) << 4));
        #pragma unroll
        for (int ni = 0; ni < 2; ni++)
            bfr[ni] = *(const bf16x8*)((const char*)Bs +
                        (wn + ni * 16 + (lane & 15)) * 64 + ((lane >> 4) << 4));
        #pragma unroll
        for (int mi = 0; mi < 2; mi++)
            #pragma unroll
            for (int ni = 0; ni < 2; ni++)
                acc[mi][ni] = __builtin_amdgcn_mfma_f32_16x16x32_bf16(
                                  af[mi], bfr[ni], acc[mi][ni], 0, 0, 0);
    }
    // epilogue with saccade-window + valid + word masks
    #pragma unroll
    for (int mi = 0; mi < 2; mi++) {
        #pragma unroll
        for (int r = 0; r < 4; r++) {
            const int t = t0 + wm + mi * 16 + ((lane >> 4) << 2) + r;
            if (t >= NT) continue;
            const int fx = fix_seq[b * NT + t];
            #pragma unroll
            for (int ni = 0; ni < 2; ni++) {
                const int w = w0 + wn + ni * 16 + (lane & 15);
                if (w >= NW) continue;
                int d = w - fx; d = d < 0 ? -d : d;
                const bool ok = (fx != 0) && (d <= 8) && (wmask[b * NW + w] != 0);
                out[(long)b * (NT * NW) + t * NW + w] = ok ? acc[mi][ni][r] : -1e9f;
            }
        }
    }
}

// ---------------------------------------------------------------------------
// dur_kernel: dur[b,t] = dot(hout[b,t,:], W_dur) + b_dur. One wave per row.
// ---------------------------------------------------------------------------
__global__ void dur_kernel(const unsigned short* __restrict__ hout,
                           const float* __restrict__ Wdur, const float* __restrict__ bdur,
                           float* __restrict__ out) {
    const int row = (int)((blockIdx.x * blockDim.x + threadIdx.x) >> 6);
    const int lane = threadIdx.x & 63;
    if (row >= MROWS) return;
    const unsigned short* hp = hout + (long)row * NH + lane * 4;
    const uint2 hv = *(const uint2*)hp;
    const float4 wv = *(const float4*)(Wdur + lane * 4);
    float s = bf2f((unsigned short)(hv.x & 0xffff)) * wv.x
            + bf2f((unsigned short)(hv.x >> 16)) * wv.y
            + bf2f((unsigned short)(hv.y & 0xffff)) * wv.z
            + bf2f((unsigned short)(hv.y >> 16)) * wv.w;
    #pragma unroll
    for (int off = 32; off >= 1; off >>= 1) s += __shfl_down(s, off);
    if (lane == 0) out[(long)NB * NT * NW + row] = s + bdur[0];
}

// ---------------------------------------------------------------------------
extern "C" void kernel_launch(void* const* d_in, const int* in_sizes, int n_in,
                              void* d_out, int out_size, void* d_ws, size_t ws_size,
                              hipStream_t stream) {
    (void)in_sizes; (void)n_in; (void)out_size; (void)ws_size;
    const float* inputs  = (const float*)d_in[0];
    const int*   fix_seq = (const int*)d_in[1];
    const float* fwe     = (const float*)d_in[2];
    const int*   lengths = (const int*)d_in[3];
    const float* emb     = (const float*)d_in[5];
    const float* Wih     = (const float*)d_in[6];
    const float* bih     = (const float*)d_in[7];
    const float* Whh     = (const float*)d_in[8];
    const float* bhh     = (const float*)d_in[9];
    const float* Wout    = (const float*)d_in[10];
    const float* bout    = (const float*)d_in[11];
    const float* Wdur    = (const float*)d_in[12];
    const float* bdur    = (const float*)d_in[13];
    float* out = (float*)d_out;

    char* ws = (char*)d_ws;
    // region layout (bytes, all 256-aligned):
    //   [0, 81,920,000)            A_bf16 [51200][800]    -> reused as proj_bf16
    //   [81,920,000, +78,643,200)  xg_bf16 [51200][768]   -> reused as fwe_bf16
    //   [160,563,200, +26,214,400) hout_bf16 [51200][256]
    //   [186,777,600, +1,228,800)  W_ih bf16
    //   [188,006,400, +393,216)    W_out bf16
    //   [188,399,616, +51,200)     word_mask u8
    //   [188,450,816, +3,072)      biasC f32 [768]
    unsigned short* Abf    = (unsigned short*)(ws);
    unsigned short* xgbf   = (unsigned short*)(ws + 81920000);
    unsigned short* hout   = (unsigned short*)(ws + 160563200);
    unsigned short* Wihbf  = (unsigned short*)(ws + 186777600);
    unsigned short* Woutbf = (unsigned short*)(ws + 188006400);
    unsigned char*  wmask  = (unsigned char*)(ws + 188399616);
    float*          biasC  = (float*)(ws + 188450816);
    unsigned short* projbf = Abf;    // A dead after gemm1
    unsigned short* fwebf  = xgbf;   // xg dead after scan

    prep1<<<2048, 256, 0, stream>>>(inputs, fix_seq, emb, Wih, Wout, bih, bhh,
                                    Abf, Wihbf, Woutbf, biasC);
    gemm_bt128<<<400 * 6, 256, 0, stream>>>(Abf, Wihbf, biasC, xgbf, MROWS, G3H, KIN);
    gru_scan<<<256, 1024, 0, stream>>>(xgbf, Whh, bhh, lengths, hout);
    gemm_bt128<<<400 * 6, 256, 0, stream>>>(hout, Woutbf, bout, projbf, MROWS, G3H, NH);
    prep2<<<12800, 256, 0, stream>>>(fwe, fwebf, wmask);
    logits_gemm<<<4096, 256, 0, stream>>>(projbf, fwebf, fix_seq, wmask, out);
    dur_kernel<<<12800, 256, 0, stream>>>(hout, Wdur, bdur, out);
}

// Round 6
// 579.363 us; speedup vs baseline: 2.1927x; 1.1988x over previous
//
#include <hip/hip_runtime.h>
#include <hip/hip_bf16.h>

typedef __attribute__((ext_vector_type(8))) short bf16x8;   // 8 bf16 in 4 VGPRs
typedef __attribute__((ext_vector_type(4))) float f32x4;    // MFMA accumulator
typedef __attribute__((ext_vector_type(4))) int   i32x4;    // i8-MFMA operand/accum

#define NB 256
#define NT 200
#define NW 200
#define NE 768
#define NH 256
#define NEMB 32
#define KIN 800           // E + EMB
#define G3H 768           // 3*H
#define MROWS 51200       // B*T

__device__ __forceinline__ float bf2f(unsigned short h) {
    return __uint_as_float(((unsigned)h) << 16);
}
__device__ __forceinline__ unsigned short f2bf(float f) {
    unsigned u = __float_as_uint(f);
    u += 0x7fff + ((u >> 16) & 1);   // RNE
    return (unsigned short)(u >> 16);
}
__device__ __forceinline__ float sigm(float x) { return 1.0f / (1.0f + __expf(-x)); }
__device__ __forceinline__ float tanh_fast(float x) {
    float e = __expf(2.0f * x);
    return 1.0f - 2.0f / (e + 1.0f);
}

// ---------------------------------------------------------------------------
// prep1: A_bf16[51200][800] = [bf16(inputs) | bf16(emb_table[fix])],
//        W_ih -> bf16 [768][800], W_out -> bf16 [768][256],
//        biasC[768] = b_ih + (row<512 ? b_hh : 0)   (b_hh r,z folded into xg)
// ---------------------------------------------------------------------------
__global__ void prep1(const float* __restrict__ inputs, const int* __restrict__ fix_seq,
                      const float* __restrict__ emb, const float* __restrict__ Wih,
                      const float* __restrict__ Wout, const float* __restrict__ bih,
                      const float* __restrict__ bhh,
                      unsigned short* __restrict__ Abf, unsigned short* __restrict__ Wihbf,
                      unsigned short* __restrict__ Woutbf, float* __restrict__ biasC) {
    const long gid0 = (long)blockIdx.x * blockDim.x + threadIdx.x;
    if (gid0 < G3H) biasC[gid0] = bih[gid0] + (gid0 < 512 ? bhh[gid0] : 0.0f);
    const long NA = (long)MROWS * 100;   // 8 cols per unit
    const long NWU = 768L * 100;
    const long NOU = 768L * 32;
    const long total = NA + NWU + NOU;
    for (long u = gid0; u < total; u += (long)gridDim.x * blockDim.x) {
        bf16x8 v;
        unsigned short* dst;
        if (u < NA) {
            long row = u / 100;
            int c8 = (int)(u % 100) * 8;
            const float* s;
            if (c8 < NE) {
                s = inputs + row * NE + c8;
            } else {
                int fx = fix_seq[row];
                s = emb + (long)fx * NEMB + (c8 - NE);
            }
            #pragma unroll
            for (int j = 0; j < 8; j++) v[j] = (short)f2bf(s[j]);
            dst = Abf + row * KIN + c8;
        } else if (u < NA + NWU) {
            long u2 = u - NA;
            long row = u2 / 100;
            int c8 = (int)(u2 % 100) * 8;
            const float* s = Wih + row * KIN + c8;
            #pragma unroll
            for (int j = 0; j < 8; j++) v[j] = (short)f2bf(s[j]);
            dst = Wihbf + row * KIN + c8;
        } else {
            long u3 = u - NA - NWU;
            long row = u3 / 32;
            int c8 = (int)(u3 % 32) * 8;
            const float* s = Wout + row * NH + c8;
            #pragma unroll
            for (int j = 0; j < 8; j++) v[j] = (short)f2bf(s[j]);
            dst = Woutbf + row * NH + c8;
        }
        *(bf16x8*)dst = v;
    }
}

// ---------------------------------------------------------------------------
// gemm_bt128: Out[M][N] (bf16) = A[M][K](bf16) * Bw[N][K](bf16)^T + bias
// BM=BN=128, BK=32, 256 threads (4 waves, each 64x64). Reg-staged LDS tiles.
// ---------------------------------------------------------------------------
__global__ void gemm_bt128(const unsigned short* __restrict__ A,
                           const unsigned short* __restrict__ Bw,
                           const float* __restrict__ bias,
                           unsigned short* __restrict__ Out,
                           int M, int N, int K) {
    __shared__ unsigned short As[128 * 32];
    __shared__ unsigned short Bs[128 * 32];
    const int nblk = N >> 7;
    const int m0 = (blockIdx.x / nblk) << 7;
    const int n0 = (blockIdx.x % nblk) << 7;
    const int tid = threadIdx.x;
    const int lane = tid & 63;
    const int wave = tid >> 6;
    const int wm = (wave >> 1) << 6;
    const int wn = (wave & 1) << 6;
    const int nk = K >> 5;

    const int srow = tid >> 1;
    const int sbyte = (tid & 1) << 5;
    const char* ga = (const char*)(A + (long)(m0 + srow) * K) + sbyte;
    const char* gb = (const char*)(Bw + (long)(n0 + srow) * K) + sbyte;
    char* la = (char*)As + srow * 64 + sbyte;
    char* lb = (char*)Bs + srow * 64 + sbyte;

    f32x4 acc[4][4] = {};

    bf16x8 ra0 = *(const bf16x8*)(ga);
    bf16x8 ra1 = *(const bf16x8*)(ga + 16);
    bf16x8 rb0 = *(const bf16x8*)(gb);
    bf16x8 rb1 = *(const bf16x8*)(gb + 16);

    for (int kt = 0; kt < nk; kt++) {
        __syncthreads();
        *(bf16x8*)(la) = ra0;      *(bf16x8*)(la + 16) = ra1;
        *(bf16x8*)(lb) = rb0;      *(bf16x8*)(lb + 16) = rb1;
        __syncthreads();
        if (kt + 1 < nk) {  // prefetch next tile into regs; latency hides under MFMA
            const char* pa = ga + (kt + 1) * 64;
            const char* pb = gb + (kt + 1) * 64;
            ra0 = *(const bf16x8*)(pa);      ra1 = *(const bf16x8*)(pa + 16);
            rb0 = *(const bf16x8*)(pb);      rb1 = *(const bf16x8*)(pb + 16);
        }
        bf16x8 af[4], bfr[4];
        #pragma unroll
        for (int mi = 0; mi < 4; mi++)
            af[mi] = *(const bf16x8*)((const char*)As +
                        (wm + mi * 16 + (lane & 15)) * 64 + ((lane >> 4) << 4));
        #pragma unroll
        for (int ni = 0; ni < 4; ni++)
            bfr[ni] = *(const bf16x8*)((const char*)Bs +
                        (wn + ni * 16 + (lane & 15)) * 64 + ((lane >> 4) << 4));
        #pragma unroll
        for (int mi = 0; mi < 4; mi++)
            #pragma unroll
            for (int ni = 0; ni < 4; ni++)
                acc[mi][ni] = __builtin_amdgcn_mfma_f32_16x16x32_bf16(
                                  af[mi], bfr[ni], acc[mi][ni], 0, 0, 0);
    }
    // epilogue: D col = lane&15, row = (lane>>4)*4 + r  (m89-verified layout)
    #pragma unroll
    for (int ni = 0; ni < 4; ni++) {
        const int col = n0 + wn + ni * 16 + (lane & 15);
        const float bv = bias[col];
        #pragma unroll
        for (int mi = 0; mi < 4; mi++) {
            const int row = m0 + wm + mi * 16 + ((lane >> 4) << 2);
            #pragma unroll
            for (int r = 0; r < 4; r++)
                Out[(long)(row + r) * N + col] = f2bf(acc[mi][ni][r] + bv);
        }
    }
}

// ---------------------------------------------------------------------------
// gru_scan: 256 blocks (1 batch each), 1024 threads (16 waves, 4/SIMD).
// int8 recurrent GEMM: mfma_i32_16x16x64_i8, K=64 -> 12 MFMA/wave/step and
// wf = 48 VGPRs/thread (3 gates x 4 ktiles x 16B). Total demand ~85 regs ->
// fits the allocator's 64+64 unified split (R4/R5 evidence: bf16's 96-reg wf
// spilled at the 64-arch-VGPR cap and re-read from L2 every step).
// W quant scale 400 (|w|<=0.3175 clamp, P~1e-10); h quant scale 127 (|h|<1
// by GRU recurrence). i32 dot exact; f32 h master in regs, so quant error
// does not compound through the state. A/B packed with the same byte->k map,
// so any HW byte-permutation cancels in the dot.
// ---------------------------------------------------------------------------
__global__ __launch_bounds__(1024)
__attribute__((amdgpu_waves_per_eu(4, 4)))
void gru_scan(const unsigned short* __restrict__ xg,   // [51200][768] bf16 (incl biasC)
              const float* __restrict__ Whh,            // [768][256] fp32
              const float* __restrict__ bhh,            // [768]
              const int* __restrict__ lengths,          // [256]
              unsigned short* __restrict__ hout) {      // [51200][256] bf16 (masked)
    __shared__ __align__(16) unsigned char h8[2][256];  // int8 h double buffer
    const int tid = threadIdx.x;
    const int lane = tid & 63;
    const int wave = tid >> 6;               // 0..15
    const int b = blockIdx.x;
    const int l = lane & 15;
    const int sub = lane >> 4;               // k-subslice 0..3
    const int c = wave * 16 + l;             // this lane's h-col

    // resident W_hh i8 B-frags: gate g, ktile kt: byte j <- W[g*256+c][kt*64+sub*16+j]
    i32x4 wf[3][4];
    #pragma unroll
    for (int g = 0; g < 3; g++) {
        const float* wr = Whh + (long)(g * 256 + c) * NH;
        #pragma unroll
        for (int kt = 0; kt < 4; kt++) {
            const float* s = wr + kt * 64 + sub * 16;
            i32x4 v;
            #pragma unroll
            for (int q = 0; q < 4; q++) {
                unsigned pack = 0;
                #pragma unroll
                for (int j = 0; j < 4; j++) {
                    int wq = (int)rintf(s[q * 4 + j] * 400.0f);
                    wq = wq > 127 ? 127 : (wq < -127 ? -127 : wq);
                    pack |= ((unsigned)(wq & 0xff)) << (8 * j);
                }
                v[q] = (int)pack;
            }
            wf[g][kt] = v;
        }
    }
    const float bhn = bhh[512 + c];          // n-gate b_hh (r,z folded into xg)
    const int len = lengths[b];
    if (tid < 128) ((unsigned*)h8)[tid] = 0u;   // zero both h buffers (512 B)

    const unsigned short* xrow = xg + (long)b * NT * G3H;
    const bool gl = (lane < 16);
    unsigned short xv0 = 0, xv1 = 0, xv2 = 0;
    if (gl) { xv0 = xrow[c]; xv1 = xrow[256 + c]; xv2 = xrow[512 + c]; }
    float hp = 0.0f;
    const float ISC = 1.0f / (400.0f * 127.0f);

    asm volatile("s_waitcnt lgkmcnt(0)" ::: "memory");
    __builtin_amdgcn_sched_barrier(0);
    __builtin_amdgcn_s_barrier();
    __builtin_amdgcn_sched_barrier(0);

    for (int t = 0; t < NT; t++) {
        // hg = h_{t-1} @ Whh^T for this wave's 16 cols x 3 gates (i8, K=64)
        const unsigned char* hb = h8[(t + 1) & 1];
        i32x4 a0 = {}, a1 = {}, a2 = {};
        #pragma unroll
        for (int kt = 0; kt < 4; kt++) {
            const i32x4 af = *(const i32x4*)(hb + kt * 64 + (sub << 4));
            a0 = __builtin_amdgcn_mfma_i32_16x16x64_i8(af, wf[0][kt], a0, 0, 0, 0);
            a1 = __builtin_amdgcn_mfma_i32_16x16x64_i8(af, wf[1][kt], a1, 0, 0, 0);
            a2 = __builtin_amdgcn_mfma_i32_16x16x64_i8(af, wf[2][kt], a2, 0, 0, 0);
        }
        if (gl) {
            const float r = sigm(bf2f(xv0) + (float)a0[0] * ISC);
            const float z = sigm(bf2f(xv1) + (float)a1[0] * ISC);
            const float n = tanh_fast(bf2f(xv2) + r * ((float)a2[0] * ISC + bhn));
            hp = (1.0f - z) * n + z * hp;
            h8[t & 1][c] = (unsigned char)((int)rintf(hp * 127.0f) & 0xff);
            hout[((long)b * NT + t) * NH + c] = (t < len) ? f2bf(hp) : (unsigned short)0;
            if (t + 1 < NT) {                 // prefetch next step's xg (floats past barrier)
                const unsigned short* xn = xrow + (long)(t + 1) * G3H;
                xv0 = xn[c]; xv1 = xn[256 + c]; xv2 = xn[512 + c];
            }
        }
        // LDS-only baton: no vmcnt drain (hout stores + xg prefetch stay in flight)
        asm volatile("s_waitcnt lgkmcnt(0)" ::: "memory");
        __builtin_amdgcn_sched_barrier(0);
        __builtin_amdgcn_s_barrier();
        __builtin_amdgcn_sched_barrier(0);
    }
}

// ---------------------------------------------------------------------------
// prep2: fwe fp32 -> bf16 + word_mask (sum|row| != 0). One wave per row.
// ---------------------------------------------------------------------------
__global__ void prep2(const float* __restrict__ fwe, unsigned short* __restrict__ fwebf,
                      unsigned char* __restrict__ wmask) {
    const int row = (int)((blockIdx.x * blockDim.x + threadIdx.x) >> 6);
    const int lane = threadIdx.x & 63;
    if (row >= MROWS) return;
    const float* s = fwe + (long)row * NE;
    unsigned short* d = fwebf + (long)row * NE;
    float asum = 0.0f;
    #pragma unroll
    for (int i = 0; i < 12; i++) {
        const float v = s[lane + i * 64];
        asum += fabsf(v);
        d[lane + i * 64] = f2bf(v);
    }
    #pragma unroll
    for (int off = 32; off >= 1; off >>= 1) asum += __shfl_xor(asum, off);
    if (lane == 0) wmask[row] = (asum != 0.0f) ? 1 : 0;
}

// ---------------------------------------------------------------------------
// logits_gemm: per-batch GEMM [200 x 768] x [200 x 768]^T with mask epilogue.
// ---------------------------------------------------------------------------
__global__ void logits_gemm(const unsigned short* __restrict__ Aproj,  // [51200][768]
                            const unsigned short* __restrict__ Bfwe,   // [51200][768]
                            const int* __restrict__ fix_seq,           // [256][200]
                            const unsigned char* __restrict__ wmask,   // [51200]
                            float* __restrict__ out) {
    __shared__ unsigned short As[64 * 32];
    __shared__ unsigned short Bs[64 * 32];
    const int blk = blockIdx.x;
    const int b = blk >> 4;
    const int mt = (blk >> 2) & 3;
    const int ntile = blk & 3;
    const int t0 = mt << 6;
    const int w0 = ntile << 6;
    const int tid = threadIdx.x;
    const int lane = tid & 63;
    const int wave = tid >> 6;
    const int wm = (wave >> 1) << 5;
    const int wn = (wave & 1) << 5;

    const int srow = tid >> 2;
    const int sbyte = (tid & 3) << 4;
    const int tA = t0 + srow > 199 ? 199 : t0 + srow;   // clamp OOB rows (masked later)
    const int wB = w0 + srow > 199 ? 199 : w0 + srow;
    const char* ga = (const char*)(Aproj + ((long)b * NT + tA) * NE) + sbyte;
    const char* gb = (const char*)(Bfwe + ((long)b * NW + wB) * NE) + sbyte;
    char* la = (char*)As + srow * 64 + sbyte;
    char* lb = (char*)Bs + srow * 64 + sbyte;

    f32x4 acc[2][2] = {};
    bf16x8 ra = *(const bf16x8*)(ga);
    bf16x8 rb = *(const bf16x8*)(gb);
    for (int kt = 0; kt < 24; kt++) {
        __syncthreads();
        *(bf16x8*)(la) = ra;
        *(bf16x8*)(lb) = rb;
        __syncthreads();
        if (kt < 23) {
            ra = *(const bf16x8*)(ga + (kt + 1) * 64);
            rb = *(const bf16x8*)(gb + (kt + 1) * 64);
        }
        bf16x8 af[2], bfr[2];
        #pragma unroll
        for (int mi = 0; mi < 2; mi++)
            af[mi] = *(const bf16x8*)((const char*)As +
                        (wm + mi * 16 + (lane & 15)) * 64 + ((lane >> 4) << 4));
        #pragma unroll
        for (int ni = 0; ni < 2; ni++)
            bfr[ni] = *(const bf16x8*)((const char*)Bs +
                        (wn + ni * 16 + (lane & 15)) * 64 + ((lane >> 4) << 4));
        #pragma unroll
        for (int mi = 0; mi < 2; mi++)
            #pragma unroll
            for (int ni = 0; ni < 2; ni++)
                acc[mi][ni] = __builtin_amdgcn_mfma_f32_16x16x32_bf16(
                                  af[mi], bfr[ni], acc[mi][ni], 0, 0, 0);
    }
    // epilogue with saccade-window + valid + word masks
    #pragma unroll
    for (int mi = 0; mi < 2; mi++) {
        #pragma unroll
        for (int r = 0; r < 4; r++) {
            const int t = t0 + wm + mi * 16 + ((lane >> 4) << 2) + r;
            if (t >= NT) continue;
            const int fx = fix_seq[b * NT + t];
            #pragma unroll
            for (int ni = 0; ni < 2; ni++) {
                const int w = w0 + wn + ni * 16 + (lane & 15);
                if (w >= NW) continue;
                int d = w - fx; d = d < 0 ? -d : d;
                const bool ok = (fx != 0) && (d <= 8) && (wmask[b * NW + w] != 0);
                out[(long)b * (NT * NW) + t * NW + w] = ok ? acc[mi][ni][r] : -1e9f;
            }
        }
    }
}

// ---------------------------------------------------------------------------
// dur_kernel: dur[b,t] = dot(hout[b,t,:], W_dur) + b_dur. One wave per row.
// ---------------------------------------------------------------------------
__global__ void dur_kernel(const unsigned short* __restrict__ hout,
                           const float* __restrict__ Wdur, const float* __restrict__ bdur,
                           float* __restrict__ out) {
    const int row = (int)((blockIdx.x * blockDim.x + threadIdx.x) >> 6);
    const int lane = threadIdx.x & 63;
    if (row >= MROWS) return;
    const unsigned short* hp = hout + (long)row * NH + lane * 4;
    const uint2 hv = *(const uint2*)hp;
    const float4 wv = *(const float4*)(Wdur + lane * 4);
    float s = bf2f((unsigned short)(hv.x & 0xffff)) * wv.x
            + bf2f((unsigned short)(hv.x >> 16)) * wv.y
            + bf2f((unsigned short)(hv.y & 0xffff)) * wv.z
            + bf2f((unsigned short)(hv.y >> 16)) * wv.w;
    #pragma unroll
    for (int off = 32; off >= 1; off >>= 1) s += __shfl_down(s, off);
    if (lane == 0) out[(long)NB * NT * NW + row] = s + bdur[0];
}

// ---------------------------------------------------------------------------
extern "C" void kernel_launch(void* const* d_in, const int* in_sizes, int n_in,
                              void* d_out, int out_size, void* d_ws, size_t ws_size,
                              hipStream_t stream) {
    (void)in_sizes; (void)n_in; (void)out_size; (void)ws_size;
    const float* inputs  = (const float*)d_in[0];
    const int*   fix_seq = (const int*)d_in[1];
    const float* fwe     = (const float*)d_in[2];
    const int*   lengths = (const int*)d_in[3];
    const float* emb     = (const float*)d_in[5];
    const float* Wih     = (const float*)d_in[6];
    const float* bih     = (const float*)d_in[7];
    const float* Whh     = (const float*)d_in[8];
    const float* bhh     = (const float*)d_in[9];
    const float* Wout    = (const float*)d_in[10];
    const float* bout    = (const float*)d_in[11];
    const float* Wdur    = (const float*)d_in[12];
    const float* bdur    = (const float*)d_in[13];
    float* out = (float*)d_out;

    char* ws = (char*)d_ws;
    // region layout (bytes, all 256-aligned):
    //   [0, 81,920,000)            A_bf16 [51200][800]    -> reused as proj_bf16
    //   [81,920,000, +78,643,200)  xg_bf16 [51200][768]   -> reused as fwe_bf16
    //   [160,563,200, +26,214,400) hout_bf16 [51200][256]
    //   [186,777,600, +1,228,800)  W_ih bf16
    //   [188,006,400, +393,216)    W_out bf16
    //   [188,399,616, +51,200)     word_mask u8
    //   [188,450,816, +3,072)      biasC f32 [768]
    unsigned short* Abf    = (unsigned short*)(ws);
    unsigned short* xgbf   = (unsigned short*)(ws + 81920000);
    unsigned short* hout   = (unsigned short*)(ws + 160563200);
    unsigned short* Wihbf  = (unsigned short*)(ws + 186777600);
    unsigned short* Woutbf = (unsigned short*)(ws + 188006400);
    unsigned char*  wmask  = (unsigned char*)(ws + 188399616);
    float*          biasC  = (float*)(ws + 188450816);
    unsigned short* projbf = Abf;    // A dead after gemm1
    unsigned short* fwebf  = xgbf;   // xg dead after scan

    prep1<<<2048, 256, 0, stream>>>(inputs, fix_seq, emb, Wih, Wout, bih, bhh,
                                    Abf, Wihbf, Woutbf, biasC);
    gemm_bt128<<<400 * 6, 256, 0, stream>>>(Abf, Wihbf, biasC, xgbf, MROWS, G3H, KIN);
    gru_scan<<<256, 1024, 0, stream>>>(xgbf, Whh, bhh, lengths, hout);
    gemm_bt128<<<400 * 6, 256, 0, stream>>>(hout, Woutbf, bout, projbf, MROWS, G3H, NH);
    prep2<<<12800, 256, 0, stream>>>(fwe, fwebf, wmask);
    logits_gemm<<<4096, 256, 0, stream>>>(projbf, fwebf, fix_seq, wmask, out);
    dur_kernel<<<12800, 256, 0, stream>>>(hout, Wdur, bdur, out);
}